// Round 14
// baseline (378.138 us; speedup 1.0000x reference)
//
#include <hip/hip_runtime.h>
#include <hip/hip_bf16.h>

#define BB 4
#define TT 2048
#define CC 1024
#define HH 8
#define DD 128
#define KTOT 2160
#define GATE0 2112
#define KP 2176            /* keys padded per batch: 34*64 */
#define NT 34              /* KV tiles per (b,h) */
#define MQ (BB*TT)
#define MKVP (BB*KP)       /* 8704 */

typedef __attribute__((ext_vector_type(4)))  float f32x4;
typedef __attribute__((ext_vector_type(16))) float f32x16;
typedef __attribute__((ext_vector_type(8)))  short bf16x8;

union PU { unsigned u[4]; bf16x8 v; };

__device__ __forceinline__ unsigned short f2bf(float f) {
    unsigned u = __float_as_uint(f);
    unsigned r = u + 0x7FFFu + ((u >> 16) & 1u);
    return (unsigned short)(r >> 16);
}
__device__ __forceinline__ unsigned pk2(float a, float b) {
    unsigned r;
    asm("v_cvt_pk_bf16_f32 %0, %1, %2" : "=v"(r) : "v"(a), "v"(b));
    return r;
}
__device__ __forceinline__ float ex2(float x) {   // exp2 = bare v_exp_f32 (input pre-scaled by log2e)
    float r;
    asm("v_exp_f32 %0, %1" : "=v"(r) : "v"(x));
    return r;
}
__device__ __forceinline__ void async16(const ushort* g, ushort* l) {
    __builtin_amdgcn_global_load_lds((const __attribute__((address_space(1))) void*)g,
                                     (__attribute__((address_space(3))) void*)l, 16, 0, 0);
}

// ---------------- 5 weights [1024][1024] f32 -> scale * W^T bf16, one launch ----------------
__global__ __launch_bounds__(256) void tcast5(const float* __restrict__ W0, const float* __restrict__ W1,
        const float* __restrict__ W2, const float* __restrict__ W3, const float* __restrict__ W4,
        ushort* __restrict__ D0, ushort* __restrict__ D1, ushort* __restrict__ D2,
        ushort* __restrict__ D3, ushort* __restrict__ D4, float alpha) {
    const float* W; ushort* Dt; float sc = 1.f;
    switch (blockIdx.z) {
        case 0:  W = W0; Dt = D0; sc = alpha; break;
        case 1:  W = W1; Dt = D1; break;
        case 2:  W = W2; Dt = D2; break;
        case 3:  W = W3; Dt = D3; break;
        default: W = W4; Dt = D4; break;
    }
    __shared__ float tile[32][33];
    const int tx = threadIdx.x & 31, ty = threadIdx.x >> 5;
    const int n0 = blockIdx.x * 32, k0 = blockIdx.y * 32;
    #pragma unroll
    for (int i = 0; i < 4; i++)
        tile[ty + i*8][tx] = W[(size_t)(k0 + ty + i*8)*CC + n0 + tx];
    __syncthreads();
    #pragma unroll
    for (int i = 0; i < 4; i++)
        Dt[(size_t)(n0 + ty + i*8)*CC + k0 + tx] = f2bf(tile[tx][ty + i*8] * sc);
}

// ---------------- gather KV rows (bf16, per-batch padded to 2176) ----------------
__global__ __launch_bounds__(256) void gather_kv(const float* __restrict__ x, const float* __restrict__ ht,
        const float* __restrict__ ha, const float* __restrict__ p, ushort* __restrict__ kvb) {
    int idx = blockIdx.x * 256 + threadIdx.x;
    int col4 = idx & 255;
    int row  = idx >> 8;
    int b = row / KP, j = row - b * KP;
    ushort4 o;
    if (j < KTOT) {
        const float* src;
        if (j < 2048)      src = x  + ((size_t)b*TT + j)*CC;
        else if (j < 2112) src = ht + ((size_t)b*64 + (j-2048))*CC;
        else if (j < 2128) src = ha + ((size_t)b*16 + (j-2112))*CC;
        else               src = p  + ((size_t)b*32 + (j-2128))*CC;
        float4 v = ((const float4*)src)[col4];
        o.x = f2bf(v.x); o.y = f2bf(v.y); o.z = f2bf(v.z); o.w = f2bf(v.w);
    } else {
        o.x = 0; o.y = 0; o.z = 0; o.w = 0;
    }
    ((ushort4*)kvb)[idx] = o;
}

// ---------------- fused QKV GEMM (128x256 tile, BK=32): [8704]x[3072] = kvb @ WqkvT^T --------
// col-tile = 256 cols; cb = col0>>10: 0=Q (row-remap, drop pad), 1=K (gate-scale), 2=V (head-T)
__global__ __launch_bounds__(256) void gemm_qkv(const ushort* __restrict__ A, const ushort* __restrict__ Wt,
        const float* __restrict__ bq, const float* __restrict__ bk, const float* __restrict__ bv,
        const float* __restrict__ gate, ushort* __restrict__ Qb, ushort* __restrict__ Kb,
        ushort* __restrict__ Vtb, float alpha) {
    __shared__ ushort As[128*32];
    __shared__ ushort Bs[256*32];
    const int t = threadIdx.x;
    const int w = t >> 6, lane = t & 63;
    const int wr = w >> 1, wc = w & 1;       // 2M x 2N waves, per-wave 64x128
    const int row0 = blockIdx.y * 128, col0 = blockIdx.x * 256;
    const int lr = lane & 15, ls = lane >> 4;
    const int cb = col0 >> 10;          // uniform per block (256 | 1024)
    const int b_ = row0 / KP;           // KP = 17*128: block-uniform
    const int jb = row0 - b_ * KP;
    const float ratio = tanhf(gate[0]);
    f32x4 acc[4][8] = {};
    for (int k0 = 0; k0 < CC; k0 += 32) {
        #pragma unroll
        for (int u = 0; u < 2; u++) {        // A: 512 slots
            int i = u*256 + t;
            int r = i >> 2, pp = i & 3;
            int s = pp ^ ((r >> 1) & 3);
            async16(A + (size_t)(row0 + r)*CC + k0 + s*8, &As[i*8]);
        }
        #pragma unroll
        for (int u = 0; u < 4; u++) {        // B: 1024 slots (256 rows)
            int i = u*256 + t;
            int r = i >> 2, pp = i & 3;
            int s = pp ^ ((r >> 1) & 3);
            async16(Wt + (size_t)(col0 + r)*CC + k0 + s*8, &Bs[i*8]);
        }
        __syncthreads();   // drains vmcnt: staged data visible
        bf16x8 af[4], bg[8];
        #pragma unroll
        for (int mi = 0; mi < 4; mi++) {
            int row = wr*64 + mi*16 + lr;
            af[mi] = *(const bf16x8*)&As[row*32 + (ls ^ ((row>>1)&3))*8];
        }
        #pragma unroll
        for (int ni = 0; ni < 8; ni++) {
            int row = wc*128 + ni*16 + lr;
            bg[ni] = *(const bf16x8*)&Bs[row*32 + (ls ^ ((row>>1)&3))*8];
        }
        #pragma unroll
        for (int mi = 0; mi < 4; mi++)
            #pragma unroll
            for (int ni = 0; ni < 8; ni++)
                acc[mi][ni] = __builtin_amdgcn_mfma_f32_16x16x32_bf16(af[mi], bg[ni], acc[mi][ni], 0, 0, 0);
        __syncthreads();   // compute done before next stage overwrites
    }
    #pragma unroll
    for (int ni = 0; ni < 8; ni++) {
        const int colw = (col0 & 1023) + wc*128 + ni*16 + lr;
        float bcol;
        if (cb == 0)      bcol = bq[colw] * alpha;
        else if (cb == 1) bcol = bk[colw];
        else              bcol = bv[colw];
        #pragma unroll
        for (int mi = 0; mi < 4; mi++) {
            f32x4 v = acc[mi][ni];
            #pragma unroll
            for (int q = 0; q < 4; q++) {
                int roff = wr*64 + mi*16 + ls*4 + q;
                int j = jb + roff;
                float o = v[q] + bcol;
                if (cb == 0) {
                    if (j < TT) Qb[(size_t)(b_*TT + j)*CC + colw] = f2bf(o);
                } else if (cb == 1) {
                    if (j >= GATE0) o *= ratio;
                    Kb[(size_t)(row0 + roff)*CC + colw] = f2bf(o);
                } else {
                    int hh = colw >> 7, dout = colw & 127;
                    Vtb[((size_t)((b_*HH + hh)*DD + dout))*KP + j] = f2bf(o);
                }
            }
        }
    }
}

// ---------------- generic bf16 MFMA GEMM (128x256 tile, BK=32): C = A @ Wt^T + bias --------
// EPI: 1 +res(f32)->bf16 out, 2 relu->f32 out
template<int EPI>
__global__ __launch_bounds__(256) void gemm_mfma(const ushort* __restrict__ A, const ushort* __restrict__ Bt,
        const float* __restrict__ bias, const float* __restrict__ res, void* __restrict__ Cv) {
    __shared__ ushort As[128*32];
    __shared__ ushort Bs[256*32];
    const int t = threadIdx.x;
    const int w = t >> 6, lane = t & 63;
    const int wr = w >> 1, wc = w & 1;
    const int row0 = blockIdx.y * 128, col0 = blockIdx.x * 256;
    const int lr = lane & 15, ls = lane >> 4;
    f32x4 acc[4][8] = {};
    for (int k0 = 0; k0 < CC; k0 += 32) {
        #pragma unroll
        for (int u = 0; u < 2; u++) {
            int i = u*256 + t;
            int r = i >> 2, pp = i & 3;
            int s = pp ^ ((r >> 1) & 3);
            async16(A + (size_t)(row0 + r)*CC + k0 + s*8, &As[i*8]);
        }
        #pragma unroll
        for (int u = 0; u < 4; u++) {
            int i = u*256 + t;
            int r = i >> 2, pp = i & 3;
            int s = pp ^ ((r >> 1) & 3);
            async16(Bt + (size_t)(col0 + r)*CC + k0 + s*8, &Bs[i*8]);
        }
        __syncthreads();
        bf16x8 af[4], bg[8];
        #pragma unroll
        for (int mi = 0; mi < 4; mi++) {
            int row = wr*64 + mi*16 + lr;
            af[mi] = *(const bf16x8*)&As[row*32 + (ls ^ ((row>>1)&3))*8];
        }
        #pragma unroll
        for (int ni = 0; ni < 8; ni++) {
            int row = wc*128 + ni*16 + lr;
            bg[ni] = *(const bf16x8*)&Bs[row*32 + (ls ^ ((row>>1)&3))*8];
        }
        #pragma unroll
        for (int mi = 0; mi < 4; mi++)
            #pragma unroll
            for (int ni = 0; ni < 8; ni++)
                acc[mi][ni] = __builtin_amdgcn_mfma_f32_16x16x32_bf16(af[mi], bg[ni], acc[mi][ni], 0, 0, 0);
        __syncthreads();
    }
    #pragma unroll
    for (int ni = 0; ni < 8; ni++) {
        const int col = col0 + wc*128 + ni*16 + lr;
        const float bcol = bias[col];
        #pragma unroll
        for (int mi = 0; mi < 4; mi++) {
            f32x4 v = acc[mi][ni];
            #pragma unroll
            for (int q = 0; q < 4; q++) {
                int row = row0 + wr*64 + mi*16 + ls*4 + q;
                float o = v[q] + bcol;
                if constexpr (EPI == 1) {
                    o += res[(size_t)row*CC + col];
                    ((ushort*)Cv)[(size_t)row*CC + col] = f2bf(o);
                } else {
                    o = fmaxf(o, 0.f);
                    ((float*)Cv)[(size_t)row*CC + col] = o;
                }
            }
        }
    }
}

// ---------------- MFMA flash attention: 4 waves x 32 q-rows, full 64-key tiles ----------------
// r8 structure + log2-domain softmax (Q pre-scaled by 1/sqrt(D)*log2e).
__global__ __launch_bounds__(256, 2) void attn_mfma(const ushort* __restrict__ Qb,
        const ushort* __restrict__ Kb, const ushort* __restrict__ Vtb,
        ushort* __restrict__ AO) {
    __shared__ ushort s_k[2][64*128];   // K tile [64 keys][128 d], 256B rows, swz (row&15)
    __shared__ ushort s_v[2][64*128];   // V paired rows: row r = [d=r: j0..63 | d=r+64: j0..63]
    __shared__ float  l_s[4][32];
    const int t = threadIdx.x;
    const int w = t >> 6, lane = t & 63;
    const int ql = lane & 31, H = lane >> 5;
    const int bid = blockIdx.x;
    const int h   = bid & 7;            // XCD-pinned head
    const int s_  = bid >> 3;
    const int b   = s_ & 3;
    const int qb0 = (s_ >> 2) * 128;

    // ---- stage Q tile [128 q][128 d] into s_k[0]|s_v[0], swizzled (row&15) ----
    #pragma unroll
    for (int u = 0; u < 8; u++) {
        int s16 = u*256 + t;
        int row = s16 >> 4, slot = s16 & 15;
        int ss = slot ^ (row & 15);
        const ushort* src = Qb + (size_t)(b*TT + qb0 + row)*CC + h*DD + ss*8;
        ushort* dst = (s16 < 1024) ? &s_k[0][s16*8] : &s_v[0][(s16 - 1024)*8];
        async16(src, dst);
    }
    asm volatile("s_waitcnt vmcnt(0)" ::: "memory");
    __builtin_amdgcn_s_barrier();
    bf16x8 qf[8];
    {
        int row = w*32 + ql;
        #pragma unroll
        for (int ds = 0; ds < 8; ds++) {
            int sp = (ds*2 + H) ^ (row & 15);
            const ushort* base = (row < 64) ? &s_k[0][row*128 + sp*8]
                                            : &s_v[0][(row-64)*128 + sp*8];
            qf[ds] = *(const bf16x8*)base;
        }
    }
    asm volatile("s_waitcnt lgkmcnt(0)" ::: "memory");
    __builtin_amdgcn_s_barrier();

    f32x16 oacc[4] = {};
    float m = -__builtin_inff(), l = 0.f;

    const size_t kbase = (size_t)(b*KP)*CC + h*DD;
    const size_t vbase = ((size_t)((b*HH + h)*DD))*KP;

    // prologue: tile 0 into buf 0 (4 K + 4 V loads per thread)
    {
        #pragma unroll
        for (int u = 0; u < 4; u++) {
            int s16 = u*256 + t;
            int row = s16 >> 4, slot = s16 & 15;
            int ss = slot ^ (row & 15);
            async16(Kb + kbase + (size_t)row*CC + ss*8, &s_k[0][s16*8]);
        }
        #pragma unroll
        for (int u = 0; u < 4; u++) {
            int s16 = u*256 + t;
            int row = s16 >> 4, slot = s16 & 15;
            int ss = slot ^ (row & 15);
            int d = row + ((ss >> 3) << 6);
            int js = ss & 7;
            async16(Vtb + vbase + (size_t)d*KP + js*8, &s_v[0][s16*8]);
        }
    }

    for (int tile = 0; tile < NT; tile++) {
        const int cur = tile & 1;
        if (tile + 1 < NT) {
            const int j0n = (tile+1) * 64;
            #pragma unroll
            for (int u = 0; u < 4; u++) {
                int s16 = u*256 + t;
                int row = s16 >> 4, slot = s16 & 15;
                int ss = slot ^ (row & 15);
                async16(Kb + kbase + (size_t)(j0n + row)*CC + ss*8, &s_k[cur^1][s16*8]);
            }
            #pragma unroll
            for (int u = 0; u < 4; u++) {
                int s16 = u*256 + t;
                int row = s16 >> 4, slot = s16 & 15;
                int ss = slot ^ (row & 15);
                int d = row + ((ss >> 3) << 6);
                int js = ss & 7;
                async16(Vtb + vbase + (size_t)d*KP + j0n + js*8, &s_v[cur^1][s16*8]);
            }
            asm volatile("s_waitcnt vmcnt(8)" ::: "memory");
        } else {
            asm volatile("s_waitcnt vmcnt(0)" ::: "memory");
        }
        __builtin_amdgcn_s_barrier();

        const ushort* ks = s_k[cur];
        const ushort* vs = s_v[cur];

        // ---- ST = K . Q^T : dual accumulator chains over key-halves ----
        f32x16 st0 = {}, st1 = {};
        #pragma unroll
        for (int ds = 0; ds < 8; ds++) {
            int g = ds*2 + H;
            bf16x8 k0 = *(const bf16x8*)&ks[ ql      *128 + (g ^ ( ql      & 15))*8];
            bf16x8 k1 = *(const bf16x8*)&ks[(32+ql)*128 + (g ^ ((32+ql) & 15))*8];
            st0 = __builtin_amdgcn_mfma_f32_32x32x16_bf16(k0, qf[ds], st0, 0, 0, 0);
            st1 = __builtin_amdgcn_mfma_f32_32x32x16_bf16(k1, qf[ds], st1, 0, 0, 0);
        }

        // ---- mask pad keys (last tile) ----
        float p0[16], p1[16];
        if (tile == NT - 1) {
            #pragma unroll
            for (int r = 0; r < 16; r++) {
                int cr = (r&3) + 8*(r>>2) + 4*H;
                p0[r] = st0[r];
                p1[r] = (cr < 16) ? st1[r] : -__builtin_inff();   // keys >= 2160 padded
            }
        } else {
            #pragma unroll
            for (int r = 0; r < 16; r++) { p0[r] = st0[r]; p1[r] = st1[r]; }
        }

        // ---- online softmax (log2 domain), wave-uniform running max ----
        float tm = -__builtin_inff();
        #pragma unroll
        for (int r = 0; r < 16; r++) tm = fmaxf(tm, fmaxf(p0[r], p1[r]));
        tm = fmaxf(tm, __shfl_xor(tm, 32));
        tm = fmaxf(tm, __shfl_xor(tm, 16));
        tm = fmaxf(tm, __shfl_xor(tm, 8));
        tm = fmaxf(tm, __shfl_xor(tm, 4));
        tm = fmaxf(tm, __shfl_xor(tm, 2));
        tm = fmaxf(tm, __shfl_xor(tm, 1));
        if (tm > m + 11.5f) {               // defer-max; 11.5 log2-units ~ e^8
            float rs = ex2(m - tm);
            m = tm;
            l *= rs;
            #pragma unroll
            for (int dt = 0; dt < 4; dt++)
                #pragma unroll
                for (int r = 0; r < 16; r++) oacc[dt][r] *= rs;
        }
        float lsum = 0.f;
        #pragma unroll
        for (int r = 0; r < 16; r++) {
            p0[r] = ex2(p0[r] - m);
            p1[r] = ex2(p1[r] - m);
            lsum += p0[r] + p1[r];
        }
        lsum += __shfl_xor(lsum, 32);
        l += lsum;

        // ---- PV: P A-fragments in-register, V paired-row B-fragments ----
        #pragma unroll
        for (int jt = 0; jt < 4; jt++) {
            const float* ps = (jt < 2) ? p0 : p1;
            const int ib = (jt & 1) * 8;
            unsigned PA0 = pk2(ps[ib+0], ps[ib+1]);
            unsigned PA1 = pk2(ps[ib+2], ps[ib+3]);
            unsigned PB0 = pk2(ps[ib+4], ps[ib+5]);
            unsigned PB1 = pk2(ps[ib+6], ps[ib+7]);
            unsigned send0 = H ? PA0 : PB0;
            unsigned send1 = H ? PA1 : PB1;
            unsigned recv0 = (unsigned)__shfl_xor((int)send0, 32);
            unsigned recv1 = (unsigned)__shfl_xor((int)send1, 32);
            PU pu;
            pu.u[0] = H ? recv0 : PA0;
            pu.u[1] = H ? recv1 : PA1;
            pu.u[2] = H ? PB0  : recv0;
            pu.u[3] = H ? PB1  : recv1;
            #pragma unroll
            for (int dt = 0; dt < 4; dt++) {
                int d = dt*32 + ql;
                int row = d & 63;
                int g = ((d >> 6) << 3) + jt*2 + H;
                int sp = g ^ (row & 15);
                bf16x8 vf = *(const bf16x8*)&vs[row*128 + sp*8];
                oacc[dt] = __builtin_amdgcn_mfma_f32_32x32x16_bf16(pu.v, vf, oacc[dt], 0, 0, 0);
            }
        }
        asm volatile("" ::: "memory");
        __builtin_amdgcn_s_barrier();
    }

    // ---- epilogue: divide by l, store bf16 ----
    l_s[w][ql] = 1.0f / l;
    __syncthreads();
    float il[16];
    #pragma unroll
    for (int r = 0; r < 16; r++) il[r] = l_s[w][(r&3) + 8*(r>>2) + 4*H];
    #pragma unroll
    for (int dt = 0; dt < 4; dt++)
        #pragma unroll
        for (int r = 0; r < 16; r++) {
            int cr = (r&3) + 8*(r>>2) + 4*H;
            size_t row = (size_t)(b*TT + qb0 + w*32 + cr);
            AO[row*CC + h*DD + dt*32 + ql] = f2bf(oacc[dt][r] * il[r]);
        }
}

// ---------------- LayerNorm over last dim (1024), bf16 in, bf16 out ----------------
__global__ __launch_bounds__(256) void ln_bf16(const ushort* __restrict__ Y, const float* __restrict__ g,
        const float* __restrict__ bb, ushort* __restrict__ Out) {
    const int row = blockIdx.x;
    const int t = threadIdx.x;
    ushort4 u4 = ((const ushort4*)(Y + (size_t)row*CC))[t];
    float v0 = __uint_as_float((unsigned)u4.x << 16);
    float v1 = __uint_as_float((unsigned)u4.y << 16);
    float v2 = __uint_as_float((unsigned)u4.z << 16);
    float v3 = __uint_as_float((unsigned)u4.w << 16);
    float s  = v0 + v1 + v2 + v3;
    float sq = v0*v0 + v1*v1 + v2*v2 + v3*v3;
    #pragma unroll
    for (int off = 32; off >= 1; off >>= 1) {
        s  += __shfl_xor(s, off);
        sq += __shfl_xor(sq, off);
    }
    __shared__ float ssum[4], ssq[4];
    const int w = t >> 6;
    if ((t & 63) == 0) { ssum[w] = s; ssq[w] = sq; }
    __syncthreads();
    s  = ssum[0] + ssum[1] + ssum[2] + ssum[3];
    sq = ssq[0]  + ssq[1]  + ssq[2]  + ssq[3];
    const float mu  = s * (1.f/1024.f);
    const float var = sq * (1.f/1024.f) - mu*mu;
    const float inv = rsqrtf(var + 1e-5f);
    float4 g4 = ((const float4*)g)[t];
    float4 b4 = ((const float4*)bb)[t];
    ushort4 o;
    o.x = f2bf((v0 - mu)*inv*g4.x + b4.x);
    o.y = f2bf((v1 - mu)*inv*g4.y + b4.y);
    o.z = f2bf((v2 - mu)*inv*g4.z + b4.z);
    o.w = f2bf((v3 - mu)*inv*g4.w + b4.w);
    ((ushort4*)(Out + (size_t)row*CC))[t] = o;
}

extern "C" void kernel_launch(void* const* d_in, const int* in_sizes, int n_in,
                              void* d_out, int out_size, void* d_ws, size_t ws_size,
                              hipStream_t stream) {
    const float* x    = (const float*)d_in[0];
    const float* h_t  = (const float*)d_in[1];
    const float* h_a  = (const float*)d_in[2];
    const float* p    = (const float*)d_in[3];
    const float* Wq   = (const float*)d_in[4];
    const float* bq   = (const float*)d_in[5];
    const float* Wk   = (const float*)d_in[6];
    const float* bk   = (const float*)d_in[7];
    const float* Wv   = (const float*)d_in[8];
    const float* bv   = (const float*)d_in[9];
    const float* Wo   = (const float*)d_in[10];
    const float* bo   = (const float*)d_in[11];
    const float* ln_g = (const float*)d_in[12];
    const float* ln_b = (const float*)d_in[13];
    const float* Wf   = (const float*)d_in[14];
    const float* bf   = (const float*)d_in[15];
    const float* gate = (const float*)d_in[16];
    float* out = (float*)d_out;

    const float alpha = 0.088388347648318447f * 1.4426950408889634f;  // 1/sqrt(D) * log2(e)

    ushort* wqT = (ushort*)d_ws;                       // wq/wk/wv contiguous = fused 3072-row Wt
    ushort* wkT = wqT + (size_t)CC*CC;
    ushort* wvT = wkT + (size_t)CC*CC;
    ushort* woT = wvT + (size_t)CC*CC;
    ushort* wfT = woT + (size_t)CC*CC;
    ushort* kvb = wfT + (size_t)CC*CC;                 // [8704][1024] bf16
    ushort* Qb  = kvb + (size_t)MKVP*CC;               // [8192][1024] bf16
    ushort* Kb  = Qb  + (size_t)MQ*CC;                 // [8704][1024] bf16
    ushort* Vtb = Kb  + (size_t)MKVP*CC;               // [B][H][128][2176] bf16
    ushort* AOb = Vtb + (size_t)MKVP*CC;               // [8192][1024] bf16
    ushort* Yb  = Kb;                                  // alias: Kb dead after attention
    ushort* YNb = kvb;                                 // alias: kvb dead after QKV GEMM

    tcast5<<<dim3(32,32,5), 256, 0, stream>>>(Wq, Wk, Wv, Wo, Wf, wqT, wkT, wvT, woT, wfT, alpha);
    gather_kv<<<MKVP, 256, 0, stream>>>(x, h_t, h_a, p, kvb);

    gemm_qkv<<<dim3(12, MKVP/128), 256, 0, stream>>>(kvb, wqT, bq, bk, bv, gate, Qb, Kb, Vtb, alpha);
    attn_mfma<<<dim3(512), 256, 0, stream>>>(Qb, Kb, Vtb, AOb);
    gemm_mfma<1><<<dim3(4, MQ/128), 256, 0, stream>>>(AOb, woT, bo, x, (void*)Yb);
    ln_bf16<<<MQ, 256, 0, stream>>>(Yb, ln_g, ln_b, YNb);
    gemm_mfma<2><<<dim3(4, MQ/128), 256, 0, stream>>>(YNb, wfT, bf, nullptr, (void*)out);
}

// Round 15
// 284.285 us; speedup vs baseline: 1.3301x; 1.3301x over previous
//
#include <hip/hip_runtime.h>
#include <hip/hip_bf16.h>

#define BB 4
#define TT 2048
#define CC 1024
#define HH 8
#define DD 128
#define KTOT 2160
#define GATE0 2112
#define KP 2176            /* keys padded per batch: 34*64 */
#define NT 34              /* KV tiles per (b,h) */
#define MQ (BB*TT)
#define MKVP (BB*KP)       /* 8704 */

typedef __attribute__((ext_vector_type(4)))  float f32x4;
typedef __attribute__((ext_vector_type(16))) float f32x16;
typedef __attribute__((ext_vector_type(8)))  short bf16x8;

union PU { unsigned u[4]; bf16x8 v; };

__device__ __forceinline__ unsigned short f2bf(float f) {
    unsigned u = __float_as_uint(f);
    unsigned r = u + 0x7FFFu + ((u >> 16) & 1u);
    return (unsigned short)(r >> 16);
}
__device__ __forceinline__ unsigned pk2(float a, float b) {
    unsigned r;
    asm("v_cvt_pk_bf16_f32 %0, %1, %2" : "=v"(r) : "v"(a), "v"(b));
    return r;
}
__device__ __forceinline__ float ex2(float x) {   // exp2 = bare v_exp_f32 (input pre-scaled by log2e)
    float r;
    asm("v_exp_f32 %0, %1" : "=v"(r) : "v"(x));
    return r;
}
__device__ __forceinline__ void async16(const ushort* g, ushort* l) {
    __builtin_amdgcn_global_load_lds((const __attribute__((address_space(1))) void*)g,
                                     (__attribute__((address_space(3))) void*)l, 16, 0, 0);
}

// ---------------- 5 weights [1024][1024] f32 -> scale * W^T bf16, one launch ----------------
__global__ __launch_bounds__(256) void tcast5(const float* __restrict__ W0, const float* __restrict__ W1,
        const float* __restrict__ W2, const float* __restrict__ W3, const float* __restrict__ W4,
        ushort* __restrict__ D0, ushort* __restrict__ D1, ushort* __restrict__ D2,
        ushort* __restrict__ D3, ushort* __restrict__ D4, float alpha) {
    const float* W; ushort* Dt; float sc = 1.f;
    switch (blockIdx.z) {
        case 0:  W = W0; Dt = D0; sc = alpha; break;
        case 1:  W = W1; Dt = D1; break;
        case 2:  W = W2; Dt = D2; break;
        case 3:  W = W3; Dt = D3; break;
        default: W = W4; Dt = D4; break;
    }
    __shared__ float tile[32][33];
    const int tx = threadIdx.x & 31, ty = threadIdx.x >> 5;
    const int n0 = blockIdx.x * 32, k0 = blockIdx.y * 32;
    #pragma unroll
    for (int i = 0; i < 4; i++)
        tile[ty + i*8][tx] = W[(size_t)(k0 + ty + i*8)*CC + n0 + tx];
    __syncthreads();
    #pragma unroll
    for (int i = 0; i < 4; i++)
        Dt[(size_t)(n0 + ty + i*8)*CC + k0 + tx] = f2bf(tile[tx][ty + i*8] * sc);
}

// ---------------- gather KV rows (bf16, per-batch padded to 2176) ----------------
__global__ __launch_bounds__(256) void gather_kv(const float* __restrict__ x, const float* __restrict__ ht,
        const float* __restrict__ ha, const float* __restrict__ p, ushort* __restrict__ kvb) {
    int idx = blockIdx.x * 256 + threadIdx.x;
    int col4 = idx & 255;
    int row  = idx >> 8;
    int b = row / KP, j = row - b * KP;
    ushort4 o;
    if (j < KTOT) {
        const float* src;
        if (j < 2048)      src = x  + ((size_t)b*TT + j)*CC;
        else if (j < 2112) src = ht + ((size_t)b*64 + (j-2048))*CC;
        else if (j < 2128) src = ha + ((size_t)b*16 + (j-2112))*CC;
        else               src = p  + ((size_t)b*32 + (j-2128))*CC;
        float4 v = ((const float4*)src)[col4];
        o.x = f2bf(v.x); o.y = f2bf(v.y); o.z = f2bf(v.z); o.w = f2bf(v.w);
    } else {
        o.x = 0; o.y = 0; o.z = 0; o.w = 0;
    }
    ((ushort4*)kvb)[idx] = o;
}

// ---------------- 8-phase 256x256 fused QKV GEMM: [8704]x[3072] = kvb @ WqkvT^T --------------
// 8 waves (2Mx4N), BK=64, 2-dbuf LDS, counted vmcnt (T3+T4), setprio (T5).
__global__ __launch_bounds__(512, 1) void gemm_qkv8(const ushort* __restrict__ A, const ushort* __restrict__ Wt,
        const float* __restrict__ bq, const float* __restrict__ bk, const float* __restrict__ bv,
        const float* __restrict__ gate, ushort* __restrict__ Qb, ushort* __restrict__ Kb,
        ushort* __restrict__ Vtb, float alpha) {
    __shared__ ushort As[2][256*64];   // 32 KiB each buf; rows = 8 x 16B slots, swz slot^(row&7)
    __shared__ ushort Bs[2][256*64];
    const int t = threadIdx.x;            // 0..511
    const int w = t >> 6, lane = t & 63;
    const int wr = w >> 2, wc = w & 3;    // 2M x 4N waves; per-wave out 128x64
    const int lr = lane & 15, ls = lane >> 4;
    const int row0 = blockIdx.y * 256, col0 = blockIdx.x * 256;
    const int cb = col0 >> 10;            // 0=Q, 1=K, 2=V (256 | 1024)
    const float ratio = tanhf(gate[0]);

    // stage one half-tile (128 rows x 64 k) = 2 loads/thread
    auto stageA = [&](int buf, int kt, int h) {
        #pragma unroll
        for (int u = 0; u < 2; u++) {
            int i = u*512 + t;                    // slot 0..1023 of the half
            int r = h*128 + (i >> 3), sl = i & 7;
            int ss = sl ^ (r & 7);
            async16(A + (size_t)(row0 + r)*CC + kt*64 + ss*8, &As[buf][(size_t)(h*1024 + i)*8]);
        }
    };
    auto stageB = [&](int buf, int kt, int h) {
        #pragma unroll
        for (int u = 0; u < 2; u++) {
            int i = u*512 + t;
            int r = h*128 + (i >> 3), sl = i & 7;
            int ss = sl ^ (r & 7);
            async16(Wt + (size_t)(col0 + r)*CC + kt*64 + ss*8, &Bs[buf][(size_t)(h*1024 + i)*8]);
        }
    };

    f32x4 acc[8][4] = {};

    // prologue: all 4 half-tiles of K-tile 0
    stageA(0, 0, 0); stageA(0, 0, 1); stageB(0, 0, 0); stageB(0, 0, 1);

    for (int kt = 0; kt < 16; kt++) {
        const int buf = kt & 1;
        const bool pre = (kt + 1 < 16);
        #pragma unroll
        for (int ph = 0; ph < 4; ph++) {
            const int q1 = ph >> 1, q2 = ph & 1;
            bf16x8 af[4][2], bg[2][2];
            if (ph == 0) {
                if (pre) {
                    stageA(buf ^ 1, kt + 1, 0);
                    asm volatile("s_waitcnt vmcnt(2)" ::: "memory");  // all of kt's data landed
                } else {
                    asm volatile("s_waitcnt vmcnt(0)" ::: "memory");
                }
                __builtin_amdgcn_s_barrier();                        // propagate to all waves
                #pragma unroll
                for (int mi = 0; mi < 4; mi++) {
                    int row = wr*128 + q1*64 + mi*16 + lr;
                    #pragma unroll
                    for (int ks = 0; ks < 2; ks++)
                        af[mi][ks] = *(const bf16x8*)&As[buf][row*64 + ((ks*4 + ls) ^ (row & 7))*8];
                }
                #pragma unroll
                for (int ni = 0; ni < 2; ni++) {
                    int row = wc*64 + q2*32 + ni*16 + lr;
                    #pragma unroll
                    for (int ks = 0; ks < 2; ks++)
                        bg[ni][ks] = *(const bf16x8*)&Bs[buf][row*64 + ((ks*4 + ls) ^ (row & 7))*8];
                }
            } else {
                #pragma unroll
                for (int mi = 0; mi < 4; mi++) {
                    int row = wr*128 + q1*64 + mi*16 + lr;
                    #pragma unroll
                    for (int ks = 0; ks < 2; ks++)
                        af[mi][ks] = *(const bf16x8*)&As[buf][row*64 + ((ks*4 + ls) ^ (row & 7))*8];
                }
                #pragma unroll
                for (int ni = 0; ni < 2; ni++) {
                    int row = wc*64 + q2*32 + ni*16 + lr;
                    #pragma unroll
                    for (int ks = 0; ks < 2; ks++)
                        bg[ni][ks] = *(const bf16x8*)&Bs[buf][row*64 + ((ks*4 + ls) ^ (row & 7))*8];
                }
                if (pre) {
                    if (ph == 1)      stageA(buf ^ 1, kt + 1, 1);
                    else if (ph == 2) stageB(buf ^ 1, kt + 1, 0);
                    else              stageB(buf ^ 1, kt + 1, 1);
                }
                __builtin_amdgcn_s_barrier();
            }
            asm volatile("s_waitcnt lgkmcnt(0)" ::: "memory");
            __builtin_amdgcn_s_setprio(1);
            #pragma unroll
            for (int mi = 0; mi < 4; mi++)
                #pragma unroll
                for (int ni = 0; ni < 2; ni++)
                    #pragma unroll
                    for (int ks = 0; ks < 2; ks++)
                        acc[q1*4 + mi][q2*2 + ni] = __builtin_amdgcn_mfma_f32_16x16x32_bf16(
                            af[mi][ks], bg[ni][ks], acc[q1*4 + mi][q2*2 + ni], 0, 0, 0);
            __builtin_amdgcn_s_setprio(0);
            __builtin_amdgcn_s_barrier();
        }
    }

    // ---- epilogue ----
    #pragma unroll
    for (int ni = 0; ni < 4; ni++) {
        const int colw = (col0 & 1023) + wc*64 + ni*16 + lr;
        float bcol;
        if (cb == 0)      bcol = bq[colw] * alpha;
        else if (cb == 1) bcol = bk[colw];
        else              bcol = bv[colw];
        #pragma unroll
        for (int mi = 0; mi < 8; mi++) {
            const int rbase = row0 + wr*128 + mi*16;     // 16-aligned: never straddles KP=2176
            const int b_ = rbase / KP;
            const int jb = rbase - b_ * KP;
            f32x4 v = acc[mi][ni];
            #pragma unroll
            for (int q = 0; q < 4; q++) {
                int roff = ls*4 + q;
                int j = jb + roff;
                float o = v[q] + bcol;
                if (cb == 0) {
                    if (j < TT) Qb[(size_t)(b_*TT + j)*CC + colw] = f2bf(o);
                } else if (cb == 1) {
                    if (j >= GATE0) o *= ratio;
                    Kb[(size_t)(rbase + roff)*CC + colw] = f2bf(o);
                } else {
                    int hh = colw >> 7, dout = colw & 127;
                    Vtb[((size_t)((b_*HH + hh)*DD + dout))*KP + j] = f2bf(o);
                }
            }
        }
    }
}

// ---------------- generic bf16 MFMA GEMM (BK=64, single-buffer): C = A @ Wt^T + bias --------
// EPI: 1 +res(f32)->bf16 out, 2 relu->f32 out
template<int EPI>
__global__ __launch_bounds__(256) void gemm_mfma(const ushort* __restrict__ A, const ushort* __restrict__ Bt,
        const float* __restrict__ bias, const float* __restrict__ res, void* __restrict__ Cv) {
    __shared__ ushort As[128*64];
    __shared__ ushort Bs[128*64];
    const int t = threadIdx.x;
    const int w = t >> 6, lane = t & 63;
    const int wr = w >> 1, wc = w & 1;
    const int row0 = blockIdx.y * 128, col0 = blockIdx.x * 128;
    const int lr = lane & 15, ls = lane >> 4;
    f32x4 acc[4][4] = {};
    for (int k0 = 0; k0 < CC; k0 += 64) {
        #pragma unroll
        for (int u = 0; u < 4; u++) {
            int i = u*256 + t;
            int r = i >> 3, sl = i & 7;
            int ss = sl ^ (r & 7);
            async16(A  + (size_t)(row0 + r)*CC + k0 + ss*8, &As[i*8]);
            async16(Bt + (size_t)(col0 + r)*CC + k0 + ss*8, &Bs[i*8]);
        }
        __syncthreads();
        #pragma unroll
        for (int ks = 0; ks < 2; ks++) {
            bf16x8 af[4], bg[4];
            #pragma unroll
            for (int mi = 0; mi < 4; mi++) {
                int row = wr*64 + mi*16 + lr;
                af[mi] = *(const bf16x8*)&As[row*64 + ((ks*4 + ls) ^ (row & 7))*8];
            }
            #pragma unroll
            for (int ni = 0; ni < 4; ni++) {
                int row = wc*64 + ni*16 + lr;
                bg[ni] = *(const bf16x8*)&Bs[row*64 + ((ks*4 + ls) ^ (row & 7))*8];
            }
            #pragma unroll
            for (int mi = 0; mi < 4; mi++)
                #pragma unroll
                for (int ni = 0; ni < 4; ni++)
                    acc[mi][ni] = __builtin_amdgcn_mfma_f32_16x16x32_bf16(af[mi], bg[ni], acc[mi][ni], 0, 0, 0);
        }
        __syncthreads();
    }
    #pragma unroll
    for (int ni = 0; ni < 4; ni++) {
        const int col = col0 + wc*64 + ni*16 + lr;
        const float bcol = bias[col];
        #pragma unroll
        for (int mi = 0; mi < 4; mi++) {
            f32x4 v = acc[mi][ni];
            #pragma unroll
            for (int q = 0; q < 4; q++) {
                int row = row0 + wr*64 + mi*16 + ls*4 + q;
                float o = v[q] + bcol;
                if constexpr (EPI == 1) {
                    o += res[(size_t)row*CC + col];
                    ((ushort*)Cv)[(size_t)row*CC + col] = f2bf(o);
                } else {
                    o = fmaxf(o, 0.f);
                    ((float*)Cv)[(size_t)row*CC + col] = o;
                }
            }
        }
    }
}

// ---------------- MFMA flash attention: 4 waves x 32 q-rows, full 64-key tiles ----------------
// r8 structure + log2-domain softmax (Q pre-scaled by 1/sqrt(D)*log2e).
__global__ __launch_bounds__(256, 2) void attn_mfma(const ushort* __restrict__ Qb,
        const ushort* __restrict__ Kb, const ushort* __restrict__ Vtb,
        ushort* __restrict__ AO) {
    __shared__ ushort s_k[2][64*128];   // K tile [64 keys][128 d], 256B rows, swz (row&15)
    __shared__ ushort s_v[2][64*128];   // V paired rows: row r = [d=r: j0..63 | d=r+64: j0..63]
    __shared__ float  l_s[4][32];
    const int t = threadIdx.x;
    const int w = t >> 6, lane = t & 63;
    const int ql = lane & 31, H = lane >> 5;
    const int bid = blockIdx.x;
    const int h   = bid & 7;            // XCD-pinned head
    const int s_  = bid >> 3;
    const int b   = s_ & 3;
    const int qb0 = (s_ >> 2) * 128;

    // ---- stage Q tile [128 q][128 d] into s_k[0]|s_v[0], swizzled (row&15) ----
    #pragma unroll
    for (int u = 0; u < 8; u++) {
        int s16 = u*256 + t;
        int row = s16 >> 4, slot = s16 & 15;
        int ss = slot ^ (row & 15);
        const ushort* src = Qb + (size_t)(b*TT + qb0 + row)*CC + h*DD + ss*8;
        ushort* dst = (s16 < 1024) ? &s_k[0][s16*8] : &s_v[0][(s16 - 1024)*8];
        async16(src, dst);
    }
    asm volatile("s_waitcnt vmcnt(0)" ::: "memory");
    __builtin_amdgcn_s_barrier();
    bf16x8 qf[8];
    {
        int row = w*32 + ql;
        #pragma unroll
        for (int ds = 0; ds < 8; ds++) {
            int sp = (ds*2 + H) ^ (row & 15);
            const ushort* base = (row < 64) ? &s_k[0][row*128 + sp*8]
                                            : &s_v[0][(row-64)*128 + sp*8];
            qf[ds] = *(const bf16x8*)base;
        }
    }
    asm volatile("s_waitcnt lgkmcnt(0)" ::: "memory");
    __builtin_amdgcn_s_barrier();

    f32x16 oacc[4] = {};
    float m = -__builtin_inff(), l = 0.f;

    const size_t kbase = (size_t)(b*KP)*CC + h*DD;
    const size_t vbase = ((size_t)((b*HH + h)*DD))*KP;

    // prologue: tile 0 into buf 0 (4 K + 4 V loads per thread)
    {
        #pragma unroll
        for (int u = 0; u < 4; u++) {
            int s16 = u*256 + t;
            int row = s16 >> 4, slot = s16 & 15;
            int ss = slot ^ (row & 15);
            async16(Kb + kbase + (size_t)row*CC + ss*8, &s_k[0][s16*8]);
        }
        #pragma unroll
        for (int u = 0; u < 4; u++) {
            int s16 = u*256 + t;
            int row = s16 >> 4, slot = s16 & 15;
            int ss = slot ^ (row & 15);
            int d = row + ((ss >> 3) << 6);
            int js = ss & 7;
            async16(Vtb + vbase + (size_t)d*KP + js*8, &s_v[0][s16*8]);
        }
    }

    for (int tile = 0; tile < NT; tile++) {
        const int cur = tile & 1;
        if (tile + 1 < NT) {
            const int j0n = (tile+1) * 64;
            #pragma unroll
            for (int u = 0; u < 4; u++) {
                int s16 = u*256 + t;
                int row = s16 >> 4, slot = s16 & 15;
                int ss = slot ^ (row & 15);
                async16(Kb + kbase + (size_t)(j0n + row)*CC + ss*8, &s_k[cur^1][s16*8]);
            }
            #pragma unroll
            for (int u = 0; u < 4; u++) {
                int s16 = u*256 + t;
                int row = s16 >> 4, slot = s16 & 15;
                int ss = slot ^ (row & 15);
                int d = row + ((ss >> 3) << 6);
                int js = ss & 7;
                async16(Vtb + vbase + (size_t)d*KP + j0n + js*8, &s_v[cur^1][s16*8]);
            }
            asm volatile("s_waitcnt vmcnt(8)" ::: "memory");
        } else {
            asm volatile("s_waitcnt vmcnt(0)" ::: "memory");
        }
        __builtin_amdgcn_s_barrier();

        const ushort* ks = s_k[cur];
        const ushort* vs = s_v[cur];

        // ---- ST = K . Q^T : dual accumulator chains over key-halves ----
        f32x16 st0 = {}, st1 = {};
        #pragma unroll
        for (int ds = 0; ds < 8; ds++) {
            int g = ds*2 + H;
            bf16x8 k0 = *(const bf16x8*)&ks[ ql      *128 + (g ^ ( ql      & 15))*8];
            bf16x8 k1 = *(const bf16x8*)&ks[(32+ql)*128 + (g ^ ((32+ql) & 15))*8];
            st0 = __builtin_amdgcn_mfma_f32_32x32x16_bf16(k0, qf[ds], st0, 0, 0, 0);
            st1 = __builtin_amdgcn_mfma_f32_32x32x16_bf16(k1, qf[ds], st1, 0, 0, 0);
        }

        // ---- mask pad keys (last tile) ----
        float p0[16], p1[16];
        if (tile == NT - 1) {
            #pragma unroll
            for (int r = 0; r < 16; r++) {
                int cr = (r&3) + 8*(r>>2) + 4*H;
                p0[r] = st0[r];
                p1[r] = (cr < 16) ? st1[r] : -__builtin_inff();   // keys >= 2160 padded
            }
        } else {
            #pragma unroll
            for (int r = 0; r < 16; r++) { p0[r] = st0[r]; p1[r] = st1[r]; }
        }

        // ---- online softmax (log2 domain), wave-uniform running max ----
        float tm = -__builtin_inff();
        #pragma unroll
        for (int r = 0; r < 16; r++) tm = fmaxf(tm, fmaxf(p0[r], p1[r]));
        tm = fmaxf(tm, __shfl_xor(tm, 32));
        tm = fmaxf(tm, __shfl_xor(tm, 16));
        tm = fmaxf(tm, __shfl_xor(tm, 8));
        tm = fmaxf(tm, __shfl_xor(tm, 4));
        tm = fmaxf(tm, __shfl_xor(tm, 2));
        tm = fmaxf(tm, __shfl_xor(tm, 1));
        if (tm > m + 11.5f) {               // defer-max; 11.5 log2-units ~ e^8
            float rs = ex2(m - tm);
            m = tm;
            l *= rs;
            #pragma unroll
            for (int dt = 0; dt < 4; dt++)
                #pragma unroll
                for (int r = 0; r < 16; r++) oacc[dt][r] *= rs;
        }
        float lsum = 0.f;
        #pragma unroll
        for (int r = 0; r < 16; r++) {
            p0[r] = ex2(p0[r] - m);
            p1[r] = ex2(p1[r] - m);
            lsum += p0[r] + p1[r];
        }
        lsum += __shfl_xor(lsum, 32);
        l += lsum;

        // ---- PV: P A-fragments in-register, V paired-row B-fragments ----
        #pragma unroll
        for (int jt = 0; jt < 4; jt++) {
            const float* ps = (jt < 2) ? p0 : p1;
            const int ib = (jt & 1) * 8;
            unsigned PA0 = pk2(ps[ib+0], ps[ib+1]);
            unsigned PA1 = pk2(ps[ib+2], ps[ib+3]);
            unsigned PB0 = pk2(ps[ib+4], ps[ib+5]);
            unsigned PB1 = pk2(ps[ib+6], ps[ib+7]);
            unsigned send0 = H ? PA0 : PB0;
            unsigned send1 = H ? PA1 : PB1;
            unsigned recv0 = (unsigned)__shfl_xor((int)send0, 32);
            unsigned recv1 = (unsigned)__shfl_xor((int)send1, 32);
            PU pu;
            pu.u[0] = H ? recv0 : PA0;
            pu.u[1] = H ? recv1 : PA1;
            pu.u[2] = H ? PB0  : recv0;
            pu.u[3] = H ? PB1  : recv1;
            #pragma unroll
            for (int dt = 0; dt < 4; dt++) {
                int d = dt*32 + ql;
                int row = d & 63;
                int g = ((d >> 6) << 3) + jt*2 + H;
                int sp = g ^ (row & 15);
                bf16x8 vf = *(const bf16x8*)&vs[row*128 + sp*8];
                oacc[dt] = __builtin_amdgcn_mfma_f32_32x32x16_bf16(pu.v, vf, oacc[dt], 0, 0, 0);
            }
        }
        asm volatile("" ::: "memory");
        __builtin_amdgcn_s_barrier();
    }

    // ---- epilogue: divide by l, store bf16 ----
    l_s[w][ql] = 1.0f / l;
    __syncthreads();
    float il[16];
    #pragma unroll
    for (int r = 0; r < 16; r++) il[r] = l_s[w][(r&3) + 8*(r>>2) + 4*H];
    #pragma unroll
    for (int dt = 0; dt < 4; dt++)
        #pragma unroll
        for (int r = 0; r < 16; r++) {
            int cr = (r&3) + 8*(r>>2) + 4*H;
            size_t row = (size_t)(b*TT + qb0 + w*32 + cr);
            AO[row*CC + h*DD + dt*32 + ql] = f2bf(oacc[dt][r] * il[r]);
        }
}

// ---------------- LayerNorm over last dim (1024), bf16 in, bf16 out ----------------
__global__ __launch_bounds__(256) void ln_bf16(const ushort* __restrict__ Y, const float* __restrict__ g,
        const float* __restrict__ bb, ushort* __restrict__ Out) {
    const int row = blockIdx.x;
    const int t = threadIdx.x;
    ushort4 u4 = ((const ushort4*)(Y + (size_t)row*CC))[t];
    float v0 = __uint_as_float((unsigned)u4.x << 16);
    float v1 = __uint_as_float((unsigned)u4.y << 16);
    float v2 = __uint_as_float((unsigned)u4.z << 16);
    float v3 = __uint_as_float((unsigned)u4.w << 16);
    float s  = v0 + v1 + v2 + v3;
    float sq = v0*v0 + v1*v1 + v2*v2 + v3*v3;
    #pragma unroll
    for (int off = 32; off >= 1; off >>= 1) {
        s  += __shfl_xor(s, off);
        sq += __shfl_xor(sq, off);
    }
    __shared__ float ssum[4], ssq[4];
    const int w = t >> 6;
    if ((t & 63) == 0) { ssum[w] = s; ssq[w] = sq; }
    __syncthreads();
    s  = ssum[0] + ssum[1] + ssum[2] + ssum[3];
    sq = ssq[0]  + ssq[1]  + ssq[2]  + ssq[3];
    const float mu  = s * (1.f/1024.f);
    const float var = sq * (1.f/1024.f) - mu*mu;
    const float inv = rsqrtf(var + 1e-5f);
    float4 g4 = ((const float4*)g)[t];
    float4 b4 = ((const float4*)bb)[t];
    ushort4 o;
    o.x = f2bf((v0 - mu)*inv*g4.x + b4.x);
    o.y = f2bf((v1 - mu)*inv*g4.y + b4.y);
    o.z = f2bf((v2 - mu)*inv*g4.z + b4.z);
    o.w = f2bf((v3 - mu)*inv*g4.w + b4.w);
    ((ushort4*)(Out + (size_t)row*CC))[t] = o;
}

extern "C" void kernel_launch(void* const* d_in, const int* in_sizes, int n_in,
                              void* d_out, int out_size, void* d_ws, size_t ws_size,
                              hipStream_t stream) {
    const float* x    = (const float*)d_in[0];
    const float* h_t  = (const float*)d_in[1];
    const float* h_a  = (const float*)d_in[2];
    const float* p    = (const float*)d_in[3];
    const float* Wq   = (const float*)d_in[4];
    const float* bq   = (const float*)d_in[5];
    const float* Wk   = (const float*)d_in[6];
    const float* bk   = (const float*)d_in[7];
    const float* Wv   = (const float*)d_in[8];
    const float* bv   = (const float*)d_in[9];
    const float* Wo   = (const float*)d_in[10];
    const float* bo   = (const float*)d_in[11];
    const float* ln_g = (const float*)d_in[12];
    const float* ln_b = (const float*)d_in[13];
    const float* Wf   = (const float*)d_in[14];
    const float* bf   = (const float*)d_in[15];
    const float* gate = (const float*)d_in[16];
    float* out = (float*)d_out;

    const float alpha = 0.088388347648318447f * 1.4426950408889634f;  // 1/sqrt(D) * log2(e)

    ushort* wqT = (ushort*)d_ws;                       // wq/wk/wv contiguous = fused 3072-row Wt
    ushort* wkT = wqT + (size_t)CC*CC;
    ushort* wvT = wkT + (size_t)CC*CC;
    ushort* woT = wvT + (size_t)CC*CC;
    ushort* wfT = woT + (size_t)CC*CC;
    ushort* kvb = wfT + (size_t)CC*CC;                 // [8704][1024] bf16
    ushort* Qb  = kvb + (size_t)MKVP*CC;               // [8192][1024] bf16
    ushort* Kb  = Qb  + (size_t)MQ*CC;                 // [8704][1024] bf16
    ushort* Vtb = Kb  + (size_t)MKVP*CC;               // [B][H][128][2176] bf16
    ushort* AOb = Vtb + (size_t)MKVP*CC;               // [8192][1024] bf16
    ushort* Yb  = Kb;                                  // alias: Kb dead after attention
    ushort* YNb = kvb;                                 // alias: kvb dead after QKV GEMM

    tcast5<<<dim3(32,32,5), 256, 0, stream>>>(Wq, Wk, Wv, Wo, Wf, wqT, wkT, wvT, woT, wfT, alpha);
    gather_kv<<<MKVP, 256, 0, stream>>>(x, h_t, h_a, p, kvb);

    gemm_qkv8<<<dim3(12, MKVP/256), 512, 0, stream>>>(kvb, wqT, bq, bk, bv, gate, Qb, Kb, Vtb, alpha);
    attn_mfma<<<dim3(512), 256, 0, stream>>>(Qb, Kb, Vtb, AOb);
    gemm_mfma<1><<<dim3(8, MQ/128), 256, 0, stream>>>(AOb, woT, bo, x, (void*)Yb);
    ln_bf16<<<MQ, 256, 0, stream>>>(Yb, ln_g, ln_b, YNb);
    gemm_mfma<2><<<dim3(8, MQ/128), 256, 0, stream>>>(YNb, wfT, bf, nullptr, (void*)out);
}

// Round 16
// 275.220 us; speedup vs baseline: 1.3739x; 1.0329x over previous
//
#include <hip/hip_runtime.h>
#include <hip/hip_bf16.h>

#define BB 4
#define TT 2048
#define CC 1024
#define HH 8
#define DD 128
#define KTOT 2160
#define GATE0 2112
#define KP 2176            /* keys padded per batch: 34*64 */
#define NT 34              /* KV tiles per (b,h) */
#define MQ (BB*TT)
#define MKVP (BB*KP)       /* 8704 */

typedef __attribute__((ext_vector_type(4)))  float f32x4;
typedef __attribute__((ext_vector_type(16))) float f32x16;
typedef __attribute__((ext_vector_type(8)))  short bf16x8;

union PU { unsigned u[4]; bf16x8 v; };

__device__ __forceinline__ unsigned short f2bf(float f) {
    unsigned u = __float_as_uint(f);
    unsigned r = u + 0x7FFFu + ((u >> 16) & 1u);
    return (unsigned short)(r >> 16);
}
__device__ __forceinline__ unsigned pk2(float a, float b) {
    unsigned r;
    asm("v_cvt_pk_bf16_f32 %0, %1, %2" : "=v"(r) : "v"(a), "v"(b));
    return r;
}
__device__ __forceinline__ float ex2(float x) {   // exp2 = bare v_exp_f32 (input pre-scaled by log2e)
    float r;
    asm("v_exp_f32 %0, %1" : "=v"(r) : "v"(x));
    return r;
}
__device__ __forceinline__ void async16(const ushort* g, ushort* l) {
    __builtin_amdgcn_global_load_lds((const __attribute__((address_space(1))) void*)g,
                                     (__attribute__((address_space(3))) void*)l, 16, 0, 0);
}

// ---------------- 5 weights [1024][1024] f32 -> scale * W^T bf16, one launch ----------------
__global__ __launch_bounds__(256) void tcast5(const float* __restrict__ W0, const float* __restrict__ W1,
        const float* __restrict__ W2, const float* __restrict__ W3, const float* __restrict__ W4,
        ushort* __restrict__ D0, ushort* __restrict__ D1, ushort* __restrict__ D2,
        ushort* __restrict__ D3, ushort* __restrict__ D4, float alpha) {
    const float* W; ushort* Dt; float sc = 1.f;
    switch (blockIdx.z) {
        case 0:  W = W0; Dt = D0; sc = alpha; break;
        case 1:  W = W1; Dt = D1; break;
        case 2:  W = W2; Dt = D2; break;
        case 3:  W = W3; Dt = D3; break;
        default: W = W4; Dt = D4; break;
    }
    __shared__ float tile[32][33];
    const int tx = threadIdx.x & 31, ty = threadIdx.x >> 5;
    const int n0 = blockIdx.x * 32, k0 = blockIdx.y * 32;
    #pragma unroll
    for (int i = 0; i < 4; i++)
        tile[ty + i*8][tx] = W[(size_t)(k0 + ty + i*8)*CC + n0 + tx];
    __syncthreads();
    #pragma unroll
    for (int i = 0; i < 4; i++)
        Dt[(size_t)(n0 + ty + i*8)*CC + k0 + tx] = f2bf(tile[tx][ty + i*8] * sc);
}

// ---------------- gather KV rows (bf16, per-batch padded to 2176) ----------------
__global__ __launch_bounds__(256) void gather_kv(const float* __restrict__ x, const float* __restrict__ ht,
        const float* __restrict__ ha, const float* __restrict__ p, ushort* __restrict__ kvb) {
    int idx = blockIdx.x * 256 + threadIdx.x;
    int col4 = idx & 255;
    int row  = idx >> 8;
    int b = row / KP, j = row - b * KP;
    ushort4 o;
    if (j < KTOT) {
        const float* src;
        if (j < 2048)      src = x  + ((size_t)b*TT + j)*CC;
        else if (j < 2112) src = ht + ((size_t)b*64 + (j-2048))*CC;
        else if (j < 2128) src = ha + ((size_t)b*16 + (j-2112))*CC;
        else               src = p  + ((size_t)b*32 + (j-2128))*CC;
        float4 v = ((const float4*)src)[col4];
        o.x = f2bf(v.x); o.y = f2bf(v.y); o.z = f2bf(v.z); o.w = f2bf(v.w);
    } else {
        o.x = 0; o.y = 0; o.z = 0; o.w = 0;
    }
    ((ushort4*)kvb)[idx] = o;
}

// ---------------- fused QKV GEMM (BK=64, single-buffer): [8704]x[3072] = kvb @ WqkvT^T -------
// col-block cb = col0>>10: 0=Q (row-remap, drop pad), 1=K (gate-scale), 2=V (head-transpose)
__global__ __launch_bounds__(256) void gemm_qkv(const ushort* __restrict__ A, const ushort* __restrict__ Wt,
        const float* __restrict__ bq, const float* __restrict__ bk, const float* __restrict__ bv,
        const float* __restrict__ gate, ushort* __restrict__ Qb, ushort* __restrict__ Kb,
        ushort* __restrict__ Vtb, float alpha) {
    __shared__ ushort As[128*64];   // 128 rows x 64 k, rows = 8 x 16B slots, swz slot^(row&7)
    __shared__ ushort Bs[128*64];
    const int t = threadIdx.x;
    const int w = t >> 6, lane = t & 63;
    const int wr = w >> 1, wc = w & 1;
    const int row0 = blockIdx.y * 128, col0 = blockIdx.x * 128;
    const int lr = lane & 15, ls = lane >> 4;
    const int cb = col0 >> 10;          // uniform per block
    const int b_ = row0 / KP;           // KP = 17*128: block-uniform
    const int jb = row0 - b_ * KP;
    if (cb == 0 && jb >= TT) return;    // Q col-panel, all-pad row block: writes nothing
    const float ratio = tanhf(gate[0]);
    f32x4 acc[4][4] = {};
    for (int k0 = 0; k0 < CC; k0 += 64) {
        #pragma unroll
        for (int u = 0; u < 4; u++) {
            int i = u*256 + t;          // 0..1023 slots
            int r = i >> 3, sl = i & 7;
            int ss = sl ^ (r & 7);
            async16(A  + (size_t)(row0 + r)*CC + k0 + ss*8, &As[i*8]);
            async16(Wt + (size_t)(col0 + r)*CC + k0 + ss*8, &Bs[i*8]);
        }
        __syncthreads();   // drains vmcnt: staged data visible
        #pragma unroll
        for (int ks = 0; ks < 2; ks++) {
            bf16x8 af[4], bg[4];
            #pragma unroll
            for (int mi = 0; mi < 4; mi++) {
                int row = wr*64 + mi*16 + lr;
                af[mi] = *(const bf16x8*)&As[row*64 + ((ks*4 + ls) ^ (row & 7))*8];
            }
            #pragma unroll
            for (int ni = 0; ni < 4; ni++) {
                int row = wc*64 + ni*16 + lr;
                bg[ni] = *(const bf16x8*)&Bs[row*64 + ((ks*4 + ls) ^ (row & 7))*8];
            }
            #pragma unroll
            for (int mi = 0; mi < 4; mi++)
                #pragma unroll
                for (int ni = 0; ni < 4; ni++)
                    acc[mi][ni] = __builtin_amdgcn_mfma_f32_16x16x32_bf16(af[mi], bg[ni], acc[mi][ni], 0, 0, 0);
        }
        __syncthreads();   // compute done before next stage overwrites
    }
    #pragma unroll
    for (int ni = 0; ni < 4; ni++) {
        const int colw = (col0 & 1023) + wc*64 + ni*16 + lr;
        float bcol;
        if (cb == 0)      bcol = bq[colw] * alpha;
        else if (cb == 1) bcol = bk[colw];
        else              bcol = bv[colw];
        #pragma unroll
        for (int mi = 0; mi < 4; mi++) {
            f32x4 v = acc[mi][ni];
            #pragma unroll
            for (int q = 0; q < 4; q++) {
                int roff = wr*64 + mi*16 + ls*4 + q;
                int j = jb + roff;
                float o = v[q] + bcol;
                if (cb == 0) {
                    if (j < TT) Qb[(size_t)(b_*TT + j)*CC + colw] = f2bf(o);
                } else if (cb == 1) {
                    if (j >= GATE0) o *= ratio;
                    Kb[(size_t)(row0 + roff)*CC + colw] = f2bf(o);
                } else {
                    int hh = colw >> 7, dout = colw & 127;
                    Vtb[((size_t)((b_*HH + hh)*DD + dout))*KP + j] = f2bf(o);
                }
            }
        }
    }
}

// ---------------- generic bf16 MFMA GEMM (BK=64, single-buffer): C = A @ Wt^T + bias --------
// EPI: 1 +res(f32)->bf16 out, 2 relu->f32 out
template<int EPI>
__global__ __launch_bounds__(256) void gemm_mfma(const ushort* __restrict__ A, const ushort* __restrict__ Bt,
        const float* __restrict__ bias, const float* __restrict__ res, void* __restrict__ Cv) {
    __shared__ ushort As[128*64];
    __shared__ ushort Bs[128*64];
    const int t = threadIdx.x;
    const int w = t >> 6, lane = t & 63;
    const int wr = w >> 1, wc = w & 1;
    const int row0 = blockIdx.y * 128, col0 = blockIdx.x * 128;
    const int lr = lane & 15, ls = lane >> 4;
    f32x4 acc[4][4] = {};
    for (int k0 = 0; k0 < CC; k0 += 64) {
        #pragma unroll
        for (int u = 0; u < 4; u++) {
            int i = u*256 + t;
            int r = i >> 3, sl = i & 7;
            int ss = sl ^ (r & 7);
            async16(A  + (size_t)(row0 + r)*CC + k0 + ss*8, &As[i*8]);
            async16(Bt + (size_t)(col0 + r)*CC + k0 + ss*8, &Bs[i*8]);
        }
        __syncthreads();
        #pragma unroll
        for (int ks = 0; ks < 2; ks++) {
            bf16x8 af[4], bg[4];
            #pragma unroll
            for (int mi = 0; mi < 4; mi++) {
                int row = wr*64 + mi*16 + lr;
                af[mi] = *(const bf16x8*)&As[row*64 + ((ks*4 + ls) ^ (row & 7))*8];
            }
            #pragma unroll
            for (int ni = 0; ni < 4; ni++) {
                int row = wc*64 + ni*16 + lr;
                bg[ni] = *(const bf16x8*)&Bs[row*64 + ((ks*4 + ls) ^ (row & 7))*8];
            }
            #pragma unroll
            for (int mi = 0; mi < 4; mi++)
                #pragma unroll
                for (int ni = 0; ni < 4; ni++)
                    acc[mi][ni] = __builtin_amdgcn_mfma_f32_16x16x32_bf16(af[mi], bg[ni], acc[mi][ni], 0, 0, 0);
        }
        __syncthreads();
    }
    #pragma unroll
    for (int ni = 0; ni < 4; ni++) {
        const int col = col0 + wc*64 + ni*16 + lr;
        const float bcol = bias[col];
        #pragma unroll
        for (int mi = 0; mi < 4; mi++) {
            f32x4 v = acc[mi][ni];
            #pragma unroll
            for (int q = 0; q < 4; q++) {
                int row = row0 + wr*64 + mi*16 + ls*4 + q;
                float o = v[q] + bcol;
                if constexpr (EPI == 1) {
                    o += res[(size_t)row*CC + col];
                    ((ushort*)Cv)[(size_t)row*CC + col] = f2bf(o);
                } else {
                    o = fmaxf(o, 0.f);
                    ((float*)Cv)[(size_t)row*CC + col] = o;
                }
            }
        }
    }
}

// ---------------- MFMA flash attention: 4 waves x 32 q-rows, full 64-key tiles ----------------
// r8 structure + log2-domain softmax (Q pre-scaled by 1/sqrt(D)*log2e).
__global__ __launch_bounds__(256, 2) void attn_mfma(const ushort* __restrict__ Qb,
        const ushort* __restrict__ Kb, const ushort* __restrict__ Vtb,
        ushort* __restrict__ AO) {
    __shared__ ushort s_k[2][64*128];   // K tile [64 keys][128 d], 256B rows, swz (row&15)
    __shared__ ushort s_v[2][64*128];   // V paired rows: row r = [d=r: j0..63 | d=r+64: j0..63]
    __shared__ float  l_s[4][32];
    const int t = threadIdx.x;
    const int w = t >> 6, lane = t & 63;
    const int ql = lane & 31, H = lane >> 5;
    const int bid = blockIdx.x;
    const int h   = bid & 7;            // XCD-pinned head
    const int s_  = bid >> 3;
    const int b   = s_ & 3;
    const int qb0 = (s_ >> 2) * 128;

    // ---- stage Q tile [128 q][128 d] into s_k[0]|s_v[0], swizzled (row&15) ----
    #pragma unroll
    for (int u = 0; u < 8; u++) {
        int s16 = u*256 + t;
        int row = s16 >> 4, slot = s16 & 15;
        int ss = slot ^ (row & 15);
        const ushort* src = Qb + (size_t)(b*TT + qb0 + row)*CC + h*DD + ss*8;
        ushort* dst = (s16 < 1024) ? &s_k[0][s16*8] : &s_v[0][(s16 - 1024)*8];
        async16(src, dst);
    }
    asm volatile("s_waitcnt vmcnt(0)" ::: "memory");
    __builtin_amdgcn_s_barrier();
    bf16x8 qf[8];
    {
        int row = w*32 + ql;
        #pragma unroll
        for (int ds = 0; ds < 8; ds++) {
            int sp = (ds*2 + H) ^ (row & 15);
            const ushort* base = (row < 64) ? &s_k[0][row*128 + sp*8]
                                            : &s_v[0][(row-64)*128 + sp*8];
            qf[ds] = *(const bf16x8*)base;
        }
    }
    asm volatile("s_waitcnt lgkmcnt(0)" ::: "memory");
    __builtin_amdgcn_s_barrier();

    f32x16 oacc[4] = {};
    float m = -__builtin_inff(), l = 0.f;

    const size_t kbase = (size_t)(b*KP)*CC + h*DD;
    const size_t vbase = ((size_t)((b*HH + h)*DD))*KP;

    // prologue: tile 0 into buf 0 (4 K + 4 V loads per thread)
    {
        #pragma unroll
        for (int u = 0; u < 4; u++) {
            int s16 = u*256 + t;
            int row = s16 >> 4, slot = s16 & 15;
            int ss = slot ^ (row & 15);
            async16(Kb + kbase + (size_t)row*CC + ss*8, &s_k[0][s16*8]);
        }
        #pragma unroll
        for (int u = 0; u < 4; u++) {
            int s16 = u*256 + t;
            int row = s16 >> 4, slot = s16 & 15;
            int ss = slot ^ (row & 15);
            int d = row + ((ss >> 3) << 6);
            int js = ss & 7;
            async16(Vtb + vbase + (size_t)d*KP + js*8, &s_v[0][s16*8]);
        }
    }

    for (int tile = 0; tile < NT; tile++) {
        const int cur = tile & 1;
        if (tile + 1 < NT) {
            const int j0n = (tile+1) * 64;
            #pragma unroll
            for (int u = 0; u < 4; u++) {
                int s16 = u*256 + t;
                int row = s16 >> 4, slot = s16 & 15;
                int ss = slot ^ (row & 15);
                async16(Kb + kbase + (size_t)(j0n + row)*CC + ss*8, &s_k[cur^1][s16*8]);
            }
            #pragma unroll
            for (int u = 0; u < 4; u++) {
                int s16 = u*256 + t;
                int row = s16 >> 4, slot = s16 & 15;
                int ss = slot ^ (row & 15);
                int d = row + ((ss >> 3) << 6);
                int js = ss & 7;
                async16(Vtb + vbase + (size_t)d*KP + j0n + js*8, &s_v[cur^1][s16*8]);
            }
            asm volatile("s_waitcnt vmcnt(8)" ::: "memory");
        } else {
            asm volatile("s_waitcnt vmcnt(0)" ::: "memory");
        }
        __builtin_amdgcn_s_barrier();

        const ushort* ks = s_k[cur];
        const ushort* vs = s_v[cur];

        // ---- ST = K . Q^T : dual accumulator chains over key-halves ----
        f32x16 st0 = {}, st1 = {};
        #pragma unroll
        for (int ds = 0; ds < 8; ds++) {
            int g = ds*2 + H;
            bf16x8 k0 = *(const bf16x8*)&ks[ ql      *128 + (g ^ ( ql      & 15))*8];
            bf16x8 k1 = *(const bf16x8*)&ks[(32+ql)*128 + (g ^ ((32+ql) & 15))*8];
            st0 = __builtin_amdgcn_mfma_f32_32x32x16_bf16(k0, qf[ds], st0, 0, 0, 0);
            st1 = __builtin_amdgcn_mfma_f32_32x32x16_bf16(k1, qf[ds], st1, 0, 0, 0);
        }

        // ---- mask pad keys (last tile) ----
        float p0[16], p1[16];
        if (tile == NT - 1) {
            #pragma unroll
            for (int r = 0; r < 16; r++) {
                int cr = (r&3) + 8*(r>>2) + 4*H;
                p0[r] = st0[r];
                p1[r] = (cr < 16) ? st1[r] : -__builtin_inff();   // keys >= 2160 padded
            }
        } else {
            #pragma unroll
            for (int r = 0; r < 16; r++) { p0[r] = st0[r]; p1[r] = st1[r]; }
        }

        // ---- online softmax (log2 domain), wave-uniform running max ----
        float tm = -__builtin_inff();
        #pragma unroll
        for (int r = 0; r < 16; r++) tm = fmaxf(tm, fmaxf(p0[r], p1[r]));
        tm = fmaxf(tm, __shfl_xor(tm, 32));
        tm = fmaxf(tm, __shfl_xor(tm, 16));
        tm = fmaxf(tm, __shfl_xor(tm, 8));
        tm = fmaxf(tm, __shfl_xor(tm, 4));
        tm = fmaxf(tm, __shfl_xor(tm, 2));
        tm = fmaxf(tm, __shfl_xor(tm, 1));
        if (tm > m + 11.5f) {               // defer-max; 11.5 log2-units ~ e^8
            float rs = ex2(m - tm);
            m = tm;
            l *= rs;
            #pragma unroll
            for (int dt = 0; dt < 4; dt++)
                #pragma unroll
                for (int r = 0; r < 16; r++) oacc[dt][r] *= rs;
        }
        float lsum = 0.f;
        #pragma unroll
        for (int r = 0; r < 16; r++) {
            p0[r] = ex2(p0[r] - m);
            p1[r] = ex2(p1[r] - m);
            lsum += p0[r] + p1[r];
        }
        lsum += __shfl_xor(lsum, 32);
        l += lsum;

        // ---- PV: P A-fragments in-register, V paired-row B-fragments ----
        #pragma unroll
        for (int jt = 0; jt < 4; jt++) {
            const float* ps = (jt < 2) ? p0 : p1;
            const int ib = (jt & 1) * 8;
            unsigned PA0 = pk2(ps[ib+0], ps[ib+1]);
            unsigned PA1 = pk2(ps[ib+2], ps[ib+3]);
            unsigned PB0 = pk2(ps[ib+4], ps[ib+5]);
            unsigned PB1 = pk2(ps[ib+6], ps[ib+7]);
            unsigned send0 = H ? PA0 : PB0;
            unsigned send1 = H ? PA1 : PB1;
            unsigned recv0 = (unsigned)__shfl_xor((int)send0, 32);
            unsigned recv1 = (unsigned)__shfl_xor((int)send1, 32);
            PU pu;
            pu.u[0] = H ? recv0 : PA0;
            pu.u[1] = H ? recv1 : PA1;
            pu.u[2] = H ? PB0  : recv0;
            pu.u[3] = H ? PB1  : recv1;
            #pragma unroll
            for (int dt = 0; dt < 4; dt++) {
                int d = dt*32 + ql;
                int row = d & 63;
                int g = ((d >> 6) << 3) + jt*2 + H;
                int sp = g ^ (row & 15);
                bf16x8 vf = *(const bf16x8*)&vs[row*128 + sp*8];
                oacc[dt] = __builtin_amdgcn_mfma_f32_32x32x16_bf16(pu.v, vf, oacc[dt], 0, 0, 0);
            }
        }
        asm volatile("" ::: "memory");
        __builtin_amdgcn_s_barrier();
    }

    // ---- epilogue: divide by l, store bf16 ----
    l_s[w][ql] = 1.0f / l;
    __syncthreads();
    float il[16];
    #pragma unroll
    for (int r = 0; r < 16; r++) il[r] = l_s[w][(r&3) + 8*(r>>2) + 4*H];
    #pragma unroll
    for (int dt = 0; dt < 4; dt++)
        #pragma unroll
        for (int r = 0; r < 16; r++) {
            int cr = (r&3) + 8*(r>>2) + 4*H;
            size_t row = (size_t)(b*TT + qb0 + w*32 + cr);
            AO[row*CC + h*DD + dt*32 + ql] = f2bf(oacc[dt][r] * il[r]);
        }
}

// ---------------- LayerNorm over last dim (1024), bf16 in, bf16 out ----------------
__global__ __launch_bounds__(256) void ln_bf16(const ushort* __restrict__ Y, const float* __restrict__ g,
        const float* __restrict__ bb, ushort* __restrict__ Out) {
    const int row = blockIdx.x;
    const int t = threadIdx.x;
    ushort4 u4 = ((const ushort4*)(Y + (size_t)row*CC))[t];
    float v0 = __uint_as_float((unsigned)u4.x << 16);
    float v1 = __uint_as_float((unsigned)u4.y << 16);
    float v2 = __uint_as_float((unsigned)u4.z << 16);
    float v3 = __uint_as_float((unsigned)u4.w << 16);
    float s  = v0 + v1 + v2 + v3;
    float sq = v0*v0 + v1*v1 + v2*v2 + v3*v3;
    #pragma unroll
    for (int off = 32; off >= 1; off >>= 1) {
        s  += __shfl_xor(s, off);
        sq += __shfl_xor(sq, off);
    }
    __shared__ float ssum[4], ssq[4];
    const int w = t >> 6;
    if ((t & 63) == 0) { ssum[w] = s; ssq[w] = sq; }
    __syncthreads();
    s  = ssum[0] + ssum[1] + ssum[2] + ssum[3];
    sq = ssq[0]  + ssq[1]  + ssq[2]  + ssq[3];
    const float mu  = s * (1.f/1024.f);
    const float var = sq * (1.f/1024.f) - mu*mu;
    const float inv = rsqrtf(var + 1e-5f);
    float4 g4 = ((const float4*)g)[t];
    float4 b4 = ((const float4*)bb)[t];
    ushort4 o;
    o.x = f2bf((v0 - mu)*inv*g4.x + b4.x);
    o.y = f2bf((v1 - mu)*inv*g4.y + b4.y);
    o.z = f2bf((v2 - mu)*inv*g4.z + b4.z);
    o.w = f2bf((v3 - mu)*inv*g4.w + b4.w);
    ((ushort4*)(Out + (size_t)row*CC))[t] = o;
}

extern "C" void kernel_launch(void* const* d_in, const int* in_sizes, int n_in,
                              void* d_out, int out_size, void* d_ws, size_t ws_size,
                              hipStream_t stream) {
    const float* x    = (const float*)d_in[0];
    const float* h_t  = (const float*)d_in[1];
    const float* h_a  = (const float*)d_in[2];
    const float* p    = (const float*)d_in[3];
    const float* Wq   = (const float*)d_in[4];
    const float* bq   = (const float*)d_in[5];
    const float* Wk   = (const float*)d_in[6];
    const float* bk   = (const float*)d_in[7];
    const float* Wv   = (const float*)d_in[8];
    const float* bv   = (const float*)d_in[9];
    const float* Wo   = (const float*)d_in[10];
    const float* bo   = (const float*)d_in[11];
    const float* ln_g = (const float*)d_in[12];
    const float* ln_b = (const float*)d_in[13];
    const float* Wf   = (const float*)d_in[14];
    const float* bf   = (const float*)d_in[15];
    const float* gate = (const float*)d_in[16];
    float* out = (float*)d_out;

    const float alpha = 0.088388347648318447f * 1.4426950408889634f;  // 1/sqrt(D) * log2(e)

    ushort* wqT = (ushort*)d_ws;                       // wq/wk/wv contiguous = fused 3072-row Wt
    ushort* wkT = wqT + (size_t)CC*CC;
    ushort* wvT = wkT + (size_t)CC*CC;
    ushort* woT = wvT + (size_t)CC*CC;
    ushort* wfT = woT + (size_t)CC*CC;
    ushort* kvb = wfT + (size_t)CC*CC;                 // [8704][1024] bf16
    ushort* Qb  = kvb + (size_t)MKVP*CC;               // [8192][1024] bf16
    ushort* Kb  = Qb  + (size_t)MQ*CC;                 // [8704][1024] bf16
    ushort* Vtb = Kb  + (size_t)MKVP*CC;               // [B][H][128][2176] bf16
    ushort* AOb = Vtb + (size_t)MKVP*CC;               // [8192][1024] bf16
    ushort* Yb  = Kb;                                  // alias: Kb dead after attention
    ushort* YNb = kvb;                                 // alias: kvb dead after QKV GEMM

    tcast5<<<dim3(32,32,5), 256, 0, stream>>>(Wq, Wk, Wv, Wo, Wf, wqT, wkT, wvT, woT, wfT, alpha);
    gather_kv<<<MKVP, 256, 0, stream>>>(x, h_t, h_a, p, kvb);

    gemm_qkv<<<dim3(24, MKVP/128), 256, 0, stream>>>(kvb, wqT, bq, bk, bv, gate, Qb, Kb, Vtb, alpha);
    attn_mfma<<<dim3(512), 256, 0, stream>>>(Qb, Kb, Vtb, AOb);
    gemm_mfma<1><<<dim3(8, MQ/128), 256, 0, stream>>>(AOb, woT, bo, x, (void*)Yb);
    ln_bf16<<<MQ, 256, 0, stream>>>(Yb, ln_g, ln_b, YNb);
    gemm_mfma<2><<<dim3(8, MQ/128), 256, 0, stream>>>(YNb, wfT, bf, nullptr, (void*)out);
}

// Round 17
// 273.059 us; speedup vs baseline: 1.3848x; 1.0079x over previous
//
#include <hip/hip_runtime.h>
#include <hip/hip_bf16.h>

#define BB 4
#define TT 2048
#define CC 1024
#define HH 8
#define DD 128
#define KTOT 2160
#define GATE0 2112
#define KP 2176            /* keys padded per batch: 34*64 */
#define NT 34              /* KV tiles per (b,h) */
#define MQ (BB*TT)
#define MKVP (BB*KP)       /* 8704 */

typedef __attribute__((ext_vector_type(4)))  float f32x4;
typedef __attribute__((ext_vector_type(16))) float f32x16;
typedef __attribute__((ext_vector_type(8)))  short bf16x8;

union PU { unsigned u[4]; bf16x8 v; };

__device__ __forceinline__ unsigned short f2bf(float f) {
    unsigned u = __float_as_uint(f);
    unsigned r = u + 0x7FFFu + ((u >> 16) & 1u);
    return (unsigned short)(r >> 16);
}
__device__ __forceinline__ unsigned pk2(float a, float b) {
    unsigned r;
    asm("v_cvt_pk_bf16_f32 %0, %1, %2" : "=v"(r) : "v"(a), "v"(b));
    return r;
}
__device__ __forceinline__ float ex2(float x) {   // exp2 = bare v_exp_f32 (input pre-scaled by log2e)
    float r;
    asm("v_exp_f32 %0, %1" : "=v"(r) : "v"(x));
    return r;
}
__device__ __forceinline__ void async16(const ushort* g, ushort* l) {
    __builtin_amdgcn_global_load_lds((const __attribute__((address_space(1))) void*)g,
                                     (__attribute__((address_space(3))) void*)l, 16, 0, 0);
}

// ---------------- 5 weights [1024][1024] f32 -> scale * W^T bf16, one launch ----------------
__global__ __launch_bounds__(256) void tcast5(const float* __restrict__ W0, const float* __restrict__ W1,
        const float* __restrict__ W2, const float* __restrict__ W3, const float* __restrict__ W4,
        ushort* __restrict__ D0, ushort* __restrict__ D1, ushort* __restrict__ D2,
        ushort* __restrict__ D3, ushort* __restrict__ D4, float alpha) {
    const float* W; ushort* Dt; float sc = 1.f;
    switch (blockIdx.z) {
        case 0:  W = W0; Dt = D0; sc = alpha; break;
        case 1:  W = W1; Dt = D1; break;
        case 2:  W = W2; Dt = D2; break;
        case 3:  W = W3; Dt = D3; break;
        default: W = W4; Dt = D4; break;
    }
    __shared__ float tile[32][33];
    const int tx = threadIdx.x & 31, ty = threadIdx.x >> 5;
    const int n0 = blockIdx.x * 32, k0 = blockIdx.y * 32;
    #pragma unroll
    for (int i = 0; i < 4; i++)
        tile[ty + i*8][tx] = W[(size_t)(k0 + ty + i*8)*CC + n0 + tx];
    __syncthreads();
    #pragma unroll
    for (int i = 0; i < 4; i++)
        Dt[(size_t)(n0 + ty + i*8)*CC + k0 + tx] = f2bf(tile[tx][ty + i*8] * sc);
}

// ---------------- gather KV rows (bf16, per-batch padded to 2176) ----------------
__global__ __launch_bounds__(256) void gather_kv(const float* __restrict__ x, const float* __restrict__ ht,
        const float* __restrict__ ha, const float* __restrict__ p, ushort* __restrict__ kvb) {
    int idx = blockIdx.x * 256 + threadIdx.x;
    int col4 = idx & 255;
    int row  = idx >> 8;
    int b = row / KP, j = row - b * KP;
    ushort4 o;
    if (j < KTOT) {
        const float* src;
        if (j < 2048)      src = x  + ((size_t)b*TT + j)*CC;
        else if (j < 2112) src = ht + ((size_t)b*64 + (j-2048))*CC;
        else if (j < 2128) src = ha + ((size_t)b*16 + (j-2112))*CC;
        else               src = p  + ((size_t)b*32 + (j-2128))*CC;
        float4 v = ((const float4*)src)[col4];
        o.x = f2bf(v.x); o.y = f2bf(v.y); o.z = f2bf(v.z); o.w = f2bf(v.w);
    } else {
        o.x = 0; o.y = 0; o.z = 0; o.w = 0;
    }
    ((ushort4*)kvb)[idx] = o;
}

// ---------------- fused QKV GEMM (BK=32, single-buffer, r10-best): [8704]x[3072] --------------
// col-block cb = col0>>10: 0=Q (row-remap, drop pad), 1=K (gate-scale), 2=V (head-transpose)
__global__ __launch_bounds__(256) void gemm_qkv(const ushort* __restrict__ A, const ushort* __restrict__ Wt,
        const float* __restrict__ bq, const float* __restrict__ bk, const float* __restrict__ bv,
        const float* __restrict__ gate, ushort* __restrict__ Qb, ushort* __restrict__ Kb,
        ushort* __restrict__ Vtb, float alpha) {
    __shared__ ushort As[128*32];
    __shared__ ushort Bs[128*32];
    const int t = threadIdx.x;
    const int w = t >> 6, lane = t & 63;
    const int wr = w >> 1, wc = w & 1;
    const int row0 = blockIdx.y * 128, col0 = blockIdx.x * 128;
    const int lr = lane & 15, ls = lane >> 4;
    const int cb = col0 >> 10;          // uniform per block
    const int b_ = row0 / KP;           // KP = 17*128: block-uniform
    const int jb = row0 - b_ * KP;
    if (cb == 0 && jb >= TT) return;    // Q col-panel, all-pad row block: writes nothing
    const float ratio = tanhf(gate[0]);
    f32x4 acc[4][4] = {};
    for (int k0 = 0; k0 < CC; k0 += 32) {
        #pragma unroll
        for (int u = 0; u < 2; u++) {
            int i = u*256 + t;
            int r = i >> 2, pp = i & 3;
            int s = pp ^ ((r >> 1) & 3);
            async16(A  + (size_t)(row0 + r)*CC + k0 + s*8, &As[(u*256 + w*64)*8]);
            async16(Wt + (size_t)(col0 + r)*CC + k0 + s*8, &Bs[(u*256 + w*64)*8]);
        }
        __syncthreads();   // drains vmcnt: staged data visible
        bf16x8 af[4], bg[4];
        #pragma unroll
        for (int mi = 0; mi < 4; mi++) {
            int row = wr*64 + mi*16 + lr;
            af[mi] = *(const bf16x8*)&As[row*32 + (ls ^ ((row>>1)&3))*8];
        }
        #pragma unroll
        for (int ni = 0; ni < 4; ni++) {
            int row = wc*64 + ni*16 + lr;
            bg[ni] = *(const bf16x8*)&Bs[row*32 + (ls ^ ((row>>1)&3))*8];
        }
        #pragma unroll
        for (int mi = 0; mi < 4; mi++)
            #pragma unroll
            for (int ni = 0; ni < 4; ni++)
                acc[mi][ni] = __builtin_amdgcn_mfma_f32_16x16x32_bf16(af[mi], bg[ni], acc[mi][ni], 0, 0, 0);
        __syncthreads();   // compute done before next stage overwrites
    }
    #pragma unroll
    for (int ni = 0; ni < 4; ni++) {
        const int colw = (col0 & 1023) + wc*64 + ni*16 + lr;
        float bcol;
        if (cb == 0)      bcol = bq[colw] * alpha;
        else if (cb == 1) bcol = bk[colw];
        else              bcol = bv[colw];
        #pragma unroll
        for (int mi = 0; mi < 4; mi++) {
            f32x4 v = acc[mi][ni];
            #pragma unroll
            for (int q = 0; q < 4; q++) {
                int roff = wr*64 + mi*16 + ls*4 + q;
                int j = jb + roff;
                float o = v[q] + bcol;
                if (cb == 0) {
                    if (j < TT) Qb[(size_t)(b_*TT + j)*CC + colw] = f2bf(o);
                } else if (cb == 1) {
                    if (j >= GATE0) o *= ratio;
                    Kb[(size_t)(row0 + roff)*CC + colw] = f2bf(o);
                } else {
                    int hh = colw >> 7, dout = colw & 127;
                    Vtb[((size_t)((b_*HH + hh)*DD + dout))*KP + j] = f2bf(o);
                }
            }
        }
    }
}

// ---------------- generic bf16 MFMA GEMM (BK=64, single-buffer): C = A @ Wt^T + bias --------
// EPI: 1 +res(f32)->bf16 out, 2 relu->f32 out
template<int EPI>
__global__ __launch_bounds__(256) void gemm_mfma(const ushort* __restrict__ A, const ushort* __restrict__ Bt,
        const float* __restrict__ bias, const float* __restrict__ res, void* __restrict__ Cv) {
    __shared__ ushort As[128*64];
    __shared__ ushort Bs[128*64];
    const int t = threadIdx.x;
    const int w = t >> 6, lane = t & 63;
    const int wr = w >> 1, wc = w & 1;
    const int row0 = blockIdx.y * 128, col0 = blockIdx.x * 128;
    const int lr = lane & 15, ls = lane >> 4;
    f32x4 acc[4][4] = {};
    for (int k0 = 0; k0 < CC; k0 += 64) {
        #pragma unroll
        for (int u = 0; u < 4; u++) {
            int i = u*256 + t;
            int r = i >> 3, sl = i & 7;
            int ss = sl ^ (r & 7);
            async16(A  + (size_t)(row0 + r)*CC + k0 + ss*8, &As[i*8]);
            async16(Bt + (size_t)(col0 + r)*CC + k0 + ss*8, &Bs[i*8]);
        }
        __syncthreads();
        #pragma unroll
        for (int ks = 0; ks < 2; ks++) {
            bf16x8 af[4], bg[4];
            #pragma unroll
            for (int mi = 0; mi < 4; mi++) {
                int row = wr*64 + mi*16 + lr;
                af[mi] = *(const bf16x8*)&As[row*64 + ((ks*4 + ls) ^ (row & 7))*8];
            }
            #pragma unroll
            for (int ni = 0; ni < 4; ni++) {
                int row = wc*64 + ni*16 + lr;
                bg[ni] = *(const bf16x8*)&Bs[row*64 + ((ks*4 + ls) ^ (row & 7))*8];
            }
            #pragma unroll
            for (int mi = 0; mi < 4; mi++)
                #pragma unroll
                for (int ni = 0; ni < 4; ni++)
                    acc[mi][ni] = __builtin_amdgcn_mfma_f32_16x16x32_bf16(af[mi], bg[ni], acc[mi][ni], 0, 0, 0);
        }
        __syncthreads();
    }
    #pragma unroll
    for (int ni = 0; ni < 4; ni++) {
        const int col = col0 + wc*64 + ni*16 + lr;
        const float bcol = bias[col];
        #pragma unroll
        for (int mi = 0; mi < 4; mi++) {
            f32x4 v = acc[mi][ni];
            #pragma unroll
            for (int q = 0; q < 4; q++) {
                int row = row0 + wr*64 + mi*16 + ls*4 + q;
                float o = v[q] + bcol;
                if constexpr (EPI == 1) {
                    o += res[(size_t)row*CC + col];
                    ((ushort*)Cv)[(size_t)row*CC + col] = f2bf(o);
                } else {
                    o = fmaxf(o, 0.f);
                    ((float*)Cv)[(size_t)row*CC + col] = o;
                }
            }
        }
    }
}

// ---------------- MFMA flash attention: 4 waves x 32 q-rows, full 64-key tiles ----------------
// r8 structure + log2-domain softmax (Q pre-scaled by 1/sqrt(D)*log2e).
__global__ __launch_bounds__(256, 2) void attn_mfma(const ushort* __restrict__ Qb,
        const ushort* __restrict__ Kb, const ushort* __restrict__ Vtb,
        ushort* __restrict__ AO) {
    __shared__ ushort s_k[2][64*128];   // K tile [64 keys][128 d], 256B rows, swz (row&15)
    __shared__ ushort s_v[2][64*128];   // V paired rows: row r = [d=r: j0..63 | d=r+64: j0..63]
    __shared__ float  l_s[4][32];
    const int t = threadIdx.x;
    const int w = t >> 6, lane = t & 63;
    const int ql = lane & 31, H = lane >> 5;
    const int bid = blockIdx.x;
    const int h   = bid & 7;            // XCD-pinned head
    const int s_  = bid >> 3;
    const int b   = s_ & 3;
    const int qb0 = (s_ >> 2) * 128;

    // ---- stage Q tile [128 q][128 d] into s_k[0]|s_v[0], swizzled (row&15) ----
    #pragma unroll
    for (int u = 0; u < 8; u++) {
        int s16 = u*256 + t;
        int row = s16 >> 4, slot = s16 & 15;
        int ss = slot ^ (row & 15);
        const ushort* src = Qb + (size_t)(b*TT + qb0 + row)*CC + h*DD + ss*8;
        ushort* dst = (s16 < 1024) ? &s_k[0][s16*8] : &s_v[0][(s16 - 1024)*8];
        async16(src, dst);
    }
    asm volatile("s_waitcnt vmcnt(0)" ::: "memory");
    __builtin_amdgcn_s_barrier();
    bf16x8 qf[8];
    {
        int row = w*32 + ql;
        #pragma unroll
        for (int ds = 0; ds < 8; ds++) {
            int sp = (ds*2 + H) ^ (row & 15);
            const ushort* base = (row < 64) ? &s_k[0][row*128 + sp*8]
                                            : &s_v[0][(row-64)*128 + sp*8];
            qf[ds] = *(const bf16x8*)base;
        }
    }
    asm volatile("s_waitcnt lgkmcnt(0)" ::: "memory");
    __builtin_amdgcn_s_barrier();

    f32x16 oacc[4] = {};
    float m = -__builtin_inff(), l = 0.f;

    const size_t kbase = (size_t)(b*KP)*CC + h*DD;
    const size_t vbase = ((size_t)((b*HH + h)*DD))*KP;

    // prologue: tile 0 into buf 0 (4 K + 4 V loads per thread)
    {
        #pragma unroll
        for (int u = 0; u < 4; u++) {
            int s16 = u*256 + t;
            int row = s16 >> 4, slot = s16 & 15;
            int ss = slot ^ (row & 15);
            async16(Kb + kbase + (size_t)row*CC + ss*8, &s_k[0][s16*8]);
        }
        #pragma unroll
        for (int u = 0; u < 4; u++) {
            int s16 = u*256 + t;
            int row = s16 >> 4, slot = s16 & 15;
            int ss = slot ^ (row & 15);
            int d = row + ((ss >> 3) << 6);
            int js = ss & 7;
            async16(Vtb + vbase + (size_t)d*KP + js*8, &s_v[0][s16*8]);
        }
    }

    for (int tile = 0; tile < NT; tile++) {
        const int cur = tile & 1;
        if (tile + 1 < NT) {
            const int j0n = (tile+1) * 64;
            #pragma unroll
            for (int u = 0; u < 4; u++) {
                int s16 = u*256 + t;
                int row = s16 >> 4, slot = s16 & 15;
                int ss = slot ^ (row & 15);
                async16(Kb + kbase + (size_t)(j0n + row)*CC + ss*8, &s_k[cur^1][s16*8]);
            }
            #pragma unroll
            for (int u = 0; u < 4; u++) {
                int s16 = u*256 + t;
                int row = s16 >> 4, slot = s16 & 15;
                int ss = slot ^ (row & 15);
                int d = row + ((ss >> 3) << 6);
                int js = ss & 7;
                async16(Vtb + vbase + (size_t)d*KP + j0n + js*8, &s_v[cur^1][s16*8]);
            }
            asm volatile("s_waitcnt vmcnt(8)" ::: "memory");
        } else {
            asm volatile("s_waitcnt vmcnt(0)" ::: "memory");
        }
        __builtin_amdgcn_s_barrier();

        const ushort* ks = s_k[cur];
        const ushort* vs = s_v[cur];

        // ---- ST = K . Q^T : dual accumulator chains over key-halves ----
        f32x16 st0 = {}, st1 = {};
        #pragma unroll
        for (int ds = 0; ds < 8; ds++) {
            int g = ds*2 + H;
            bf16x8 k0 = *(const bf16x8*)&ks[ ql      *128 + (g ^ ( ql      & 15))*8];
            bf16x8 k1 = *(const bf16x8*)&ks[(32+ql)*128 + (g ^ ((32+ql) & 15))*8];
            st0 = __builtin_amdgcn_mfma_f32_32x32x16_bf16(k0, qf[ds], st0, 0, 0, 0);
            st1 = __builtin_amdgcn_mfma_f32_32x32x16_bf16(k1, qf[ds], st1, 0, 0, 0);
        }

        // ---- mask pad keys (last tile) ----
        float p0[16], p1[16];
        if (tile == NT - 1) {
            #pragma unroll
            for (int r = 0; r < 16; r++) {
                int cr = (r&3) + 8*(r>>2) + 4*H;
                p0[r] = st0[r];
                p1[r] = (cr < 16) ? st1[r] : -__builtin_inff();   // keys >= 2160 padded
            }
        } else {
            #pragma unroll
            for (int r = 0; r < 16; r++) { p0[r] = st0[r]; p1[r] = st1[r]; }
        }

        // ---- online softmax (log2 domain), wave-uniform running max ----
        float tm = -__builtin_inff();
        #pragma unroll
        for (int r = 0; r < 16; r++) tm = fmaxf(tm, fmaxf(p0[r], p1[r]));
        tm = fmaxf(tm, __shfl_xor(tm, 32));
        tm = fmaxf(tm, __shfl_xor(tm, 16));
        tm = fmaxf(tm, __shfl_xor(tm, 8));
        tm = fmaxf(tm, __shfl_xor(tm, 4));
        tm = fmaxf(tm, __shfl_xor(tm, 2));
        tm = fmaxf(tm, __shfl_xor(tm, 1));
        if (tm > m + 11.5f) {               // defer-max; 11.5 log2-units ~ e^8
            float rs = ex2(m - tm);
            m = tm;
            l *= rs;
            #pragma unroll
            for (int dt = 0; dt < 4; dt++)
                #pragma unroll
                for (int r = 0; r < 16; r++) oacc[dt][r] *= rs;
        }
        float lsum = 0.f;
        #pragma unroll
        for (int r = 0; r < 16; r++) {
            p0[r] = ex2(p0[r] - m);
            p1[r] = ex2(p1[r] - m);
            lsum += p0[r] + p1[r];
        }
        lsum += __shfl_xor(lsum, 32);
        l += lsum;

        // ---- PV: P A-fragments in-register, V paired-row B-fragments ----
        #pragma unroll
        for (int jt = 0; jt < 4; jt++) {
            const float* ps = (jt < 2) ? p0 : p1;
            const int ib = (jt & 1) * 8;
            unsigned PA0 = pk2(ps[ib+0], ps[ib+1]);
            unsigned PA1 = pk2(ps[ib+2], ps[ib+3]);
            unsigned PB0 = pk2(ps[ib+4], ps[ib+5]);
            unsigned PB1 = pk2(ps[ib+6], ps[ib+7]);
            unsigned send0 = H ? PA0 : PB0;
            unsigned send1 = H ? PA1 : PB1;
            unsigned recv0 = (unsigned)__shfl_xor((int)send0, 32);
            unsigned recv1 = (unsigned)__shfl_xor((int)send1, 32);
            PU pu;
            pu.u[0] = H ? recv0 : PA0;
            pu.u[1] = H ? recv1 : PA1;
            pu.u[2] = H ? PB0  : recv0;
            pu.u[3] = H ? PB1  : recv1;
            #pragma unroll
            for (int dt = 0; dt < 4; dt++) {
                int d = dt*32 + ql;
                int row = d & 63;
                int g = ((d >> 6) << 3) + jt*2 + H;
                int sp = g ^ (row & 15);
                bf16x8 vf = *(const bf16x8*)&vs[row*128 + sp*8];
                oacc[dt] = __builtin_amdgcn_mfma_f32_32x32x16_bf16(pu.v, vf, oacc[dt], 0, 0, 0);
            }
        }
        asm volatile("" ::: "memory");
        __builtin_amdgcn_s_barrier();
    }

    // ---- epilogue: divide by l, store bf16 ----
    l_s[w][ql] = 1.0f / l;
    __syncthreads();
    float il[16];
    #pragma unroll
    for (int r = 0; r < 16; r++) il[r] = l_s[w][(r&3) + 8*(r>>2) + 4*H];
    #pragma unroll
    for (int dt = 0; dt < 4; dt++)
        #pragma unroll
        for (int r = 0; r < 16; r++) {
            int cr = (r&3) + 8*(r>>2) + 4*H;
            size_t row = (size_t)(b*TT + qb0 + w*32 + cr);
            AO[row*CC + h*DD + dt*32 + ql] = f2bf(oacc[dt][r] * il[r]);
        }
}

// ---------------- LayerNorm over last dim (1024), bf16 in, bf16 out ----------------
__global__ __launch_bounds__(256) void ln_bf16(const ushort* __restrict__ Y, const float* __restrict__ g,
        const float* __restrict__ bb, ushort* __restrict__ Out) {
    const int row = blockIdx.x;
    const int t = threadIdx.x;
    ushort4 u4 = ((const ushort4*)(Y + (size_t)row*CC))[t];
    float v0 = __uint_as_float((unsigned)u4.x << 16);
    float v1 = __uint_as_float((unsigned)u4.y << 16);
    float v2 = __uint_as_float((unsigned)u4.z << 16);
    float v3 = __uint_as_float((unsigned)u4.w << 16);
    float s  = v0 + v1 + v2 + v3;
    float sq = v0*v0 + v1*v1 + v2*v2 + v3*v3;
    #pragma unroll
    for (int off = 32; off >= 1; off >>= 1) {
        s  += __shfl_xor(s, off);
        sq += __shfl_xor(sq, off);
    }
    __shared__ float ssum[4], ssq[4];
    const int w = t >> 6;
    if ((t & 63) == 0) { ssum[w] = s; ssq[w] = sq; }
    __syncthreads();
    s  = ssum[0] + ssum[1] + ssum[2] + ssum[3];
    sq = ssq[0]  + ssq[1]  + ssq[2]  + ssq[3];
    const float mu  = s * (1.f/1024.f);
    const float var = sq * (1.f/1024.f) - mu*mu;
    const float inv = rsqrtf(var + 1e-5f);
    float4 g4 = ((const float4*)g)[t];
    float4 b4 = ((const float4*)bb)[t];
    ushort4 o;
    o.x = f2bf((v0 - mu)*inv*g4.x + b4.x);
    o.y = f2bf((v1 - mu)*inv*g4.y + b4.y);
    o.z = f2bf((v2 - mu)*inv*g4.z + b4.z);
    o.w = f2bf((v3 - mu)*inv*g4.w + b4.w);
    ((ushort4*)(Out + (size_t)row*CC))[t] = o;
}

extern "C" void kernel_launch(void* const* d_in, const int* in_sizes, int n_in,
                              void* d_out, int out_size, void* d_ws, size_t ws_size,
                              hipStream_t stream) {
    const float* x    = (const float*)d_in[0];
    const float* h_t  = (const float*)d_in[1];
    const float* h_a  = (const float*)d_in[2];
    const float* p    = (const float*)d_in[3];
    const float* Wq   = (const float*)d_in[4];
    const float* bq   = (const float*)d_in[5];
    const float* Wk   = (const float*)d_in[6];
    const float* bk   = (const float*)d_in[7];
    const float* Wv   = (const float*)d_in[8];
    const float* bv   = (const float*)d_in[9];
    const float* Wo   = (const float*)d_in[10];
    const float* bo   = (const float*)d_in[11];
    const float* ln_g = (const float*)d_in[12];
    const float* ln_b = (const float*)d_in[13];
    const float* Wf   = (const float*)d_in[14];
    const float* bf   = (const float*)d_in[15];
    const float* gate = (const float*)d_in[16];
    float* out = (float*)d_out;

    const float alpha = 0.088388347648318447f * 1.4426950408889634f;  // 1/sqrt(D) * log2(e)

    ushort* wqT = (ushort*)d_ws;                       // wq/wk/wv contiguous = fused 3072-row Wt
    ushort* wkT = wqT + (size_t)CC*CC;
    ushort* wvT = wkT + (size_t)CC*CC;
    ushort* woT = wvT + (size_t)CC*CC;
    ushort* wfT = woT + (size_t)CC*CC;
    ushort* kvb = wfT + (size_t)CC*CC;                 // [8704][1024] bf16
    ushort* Qb  = kvb + (size_t)MKVP*CC;               // [8192][1024] bf16
    ushort* Kb  = Qb  + (size_t)MQ*CC;                 // [8704][1024] bf16
    ushort* Vtb = Kb  + (size_t)MKVP*CC;               // [B][H][128][2176] bf16
    ushort* AOb = Vtb + (size_t)MKVP*CC;               // [8192][1024] bf16
    ushort* Yb  = Kb;                                  // alias: Kb dead after attention
    ushort* YNb = kvb;                                 // alias: kvb dead after QKV GEMM

    tcast5<<<dim3(32,32,5), 256, 0, stream>>>(Wq, Wk, Wv, Wo, Wf, wqT, wkT, wvT, woT, wfT, alpha);
    gather_kv<<<MKVP, 256, 0, stream>>>(x, h_t, h_a, p, kvb);

    gemm_qkv<<<dim3(24, MKVP/128), 256, 0, stream>>>(kvb, wqT, bq, bk, bv, gate, Qb, Kb, Vtb, alpha);
    attn_mfma<<<dim3(512), 256, 0, stream>>>(Qb, Kb, Vtb, AOb);
    gemm_mfma<1><<<dim3(8, MQ/128), 256, 0, stream>>>(AOb, woT, bo, x, (void*)Yb);
    ln_bf16<<<MQ, 256, 0, stream>>>(Yb, ln_g, ln_b, YNb);
    gemm_mfma<2><<<dim3(8, MQ/128), 256, 0, stream>>>(YNb, wfT, bf, nullptr, (void*)out);
}